// Round 7
// baseline (267.636 us; speedup 1.0000x reference)
//
#include <hip/hip_runtime.h>

#define NB 1024
#define NV 6890
#define VP 6912       // NV padded to mult of 32
#define NJ 24
#define NBETA 10
#define NPOSE 207
#define NK 19
#define NKJ 456       // 19*24
#define NCOL 1368     // 3*456
#define KR 218
#define AR 219        // GEMM A rows incl ones-row
#define VSTR 20670    // 3*NV
#define RTP 16        // row frags (256 rows padded)
#define NVC 216       // v chunks of 32 (VP/32)
#define CFP 32        // col frags (512 cols padded)
#define KSPLIT 24
#define KSTEPS 9      // (VP/KSPLIT)/32

typedef __attribute__((ext_vector_type(8))) short bf16x8;
typedef __attribute__((ext_vector_type(4))) float f32x4;

// ---- workspace layout ----
#define AP_PLANE ((size_t)3*RTP*NVC*64*8)   // 5,308,416 shorts
#define BP_PLANE ((size_t)CFP*NVC*64*8)     // 3,538,944 shorts
#define USH_TOTAL (2*AP_PLANE + 2*BP_PLANE) // 17,694,720 shorts = 35.4 MB
#define SZ_OUT   ((size_t)AR*NCOL)
#define SZ_COEF  ((size_t)KR*NB)
#define SZ_AW    ((size_t)NB*288)
#define SZ_JS    (11ull*24*3)
#define SZ_M     ((size_t)NB*NCOL)

__device__ inline void bf_split(float x, unsigned short& h, unsigned short& l) {
    unsigned u = __float_as_uint(x);
    h = (unsigned short)(u >> 16);
    float hf = __uint_as_float((unsigned)h << 16);
    float lf = x - hf;
    l = (unsigned short)(__float_as_uint(lf) >> 16);
}

// A packed: AP[a][rt][vc][lane=(kchunk)*16+(row&15)][e] = bf16(A[a][rt*16+row][vc*32+kchunk*8+e])
// thread = (r, vch of 8 v's); reads 24 contiguous floats once, emits all 3 a's.
__global__ void k_at2(const float* __restrict__ pd, const float* __restrict__ sd,
                      const float* __restrict__ vt,
                      unsigned short* __restrict__ APH, unsigned short* __restrict__ APL) {
    int idx = blockIdx.x * 256 + threadIdx.x;
    const int TOT = 256 * 864;
    if (idx >= TOT) return;
    int r = idx / 864;
    int vch = idx - r * 864;
    int v0 = vch * 8;

    float f[24];
    if (r >= AR) {
#pragma unroll
        for (int i = 0; i < 24; i++) f[i] = 0.f;
    } else if (r == 218) {
#pragma unroll
        for (int i = 0; i < 24; i++) f[i] = (v0 + i / 3 < NV) ? 1.0f : 0.f;
    } else {
        const float* src = (r < NPOSE) ? (pd + (size_t)r * VSTR)
                         : (r < 217)   ? (sd + (size_t)(r - NPOSE) * VSTR)
                                       : vt;
        if (v0 + 8 <= NV) {
            const float2* p = (const float2*)(src + 3 * v0);
#pragma unroll
            for (int q = 0; q < 12; q++) {
                float2 t = p[q];
                f[2 * q] = t.x; f[2 * q + 1] = t.y;
            }
        } else {
#pragma unroll
            for (int i = 0; i < 24; i++)
                f[i] = (v0 + i / 3 < NV) ? src[3 * v0 + i] : 0.f;
        }
    }

    int rt = r >> 4, rl = r & 15;
    int vc = vch >> 2, lh = vch & 3;
    int lane = lh * 16 + rl;
#pragma unroll
    for (int a = 0; a < 3; a++) {
        union { unsigned short u[8]; int4 v; } H, L;
#pragma unroll
        for (int e = 0; e < 8; e++) bf_split(f[3 * e + a], H.u[e], L.u[e]);
        size_t off = (((size_t)(a * RTP + rt) * NVC + vc) * 64 + lane) * 8;
        *(int4*)&APH[off] = H.v;
        *(int4*)&APL[off] = L.v;
    }
}

// B packed: BP[cf][vc][lane=(kchunk)*16+(col&15)][e] = bf16(jr[v,k]*w[v,j]), col=cf*16+(col&15)
__global__ void k_cw2(const float* __restrict__ jr, const float* __restrict__ w,
                      unsigned short* __restrict__ BPH, unsigned short* __restrict__ BPL) {
    int idx = blockIdx.x * 256 + threadIdx.x;
    const int TOT = 512 * 864;
    if (idx >= TOT) return;
    int col = idx / 864;
    int vch = idx - col * 864;
    int v0 = vch * 8;
    int k = col / NJ, j = col - k * NJ;
    bool okc = (col < NKJ);

    union { unsigned short u[8]; int4 v; } H, L;
#pragma unroll
    for (int e = 0; e < 8; e++) {
        int v = v0 + e;
        float val = (okc && v < NV) ? jr[v * NK + k] * w[v * NJ + j] : 0.f;
        bf_split(val, H.u[e], L.u[e]);
    }
    int cf = col >> 4;
    int lane = (vch & 3) * 16 + (col & 15);
    int vc = vch >> 2;
    size_t off = (((size_t)cf * NVC + vc) * 64 + lane) * 8;
    *(int4*)&BPH[off] = H.v;
    *(int4*)&BPL[off] = L.v;
}

// JS reduction (unchanged from r6)
__global__ __launch_bounds__(256) void k_js2(const float* __restrict__ Jreg,
                                             const float* __restrict__ sd,
                                             const float* __restrict__ vt,
                                             float* __restrict__ JS) {
    int row = blockIdx.x % 11;
    int c   = blockIdx.x / 11;
    int tid = threadIdx.x;
    int lane = tid & 63;
    const float* src = (row < NBETA) ? (sd + (size_t)row * VSTR) : vt;

    float acc[72];
#pragma unroll
    for (int o = 0; o < 72; o++) acc[o] = 0.f;

    for (int iv = 0; iv < 4; ++iv) {
        int v = c * 1024 + iv * 256 + tid;
        float jrg[24];
        float s0 = 0.f, s1 = 0.f, s2 = 0.f;
        if (v < NV) {
#pragma unroll
            for (int q = 0; q < 6; q++) {
                float4 f = *(const float4*)&Jreg[v * NJ + q * 4];
                jrg[q * 4 + 0] = f.x; jrg[q * 4 + 1] = f.y;
                jrg[q * 4 + 2] = f.z; jrg[q * 4 + 3] = f.w;
            }
            s0 = src[3 * v]; s1 = src[3 * v + 1]; s2 = src[3 * v + 2];
        } else {
#pragma unroll
            for (int q = 0; q < 24; q++) jrg[q] = 0.f;
        }
#pragma unroll
        for (int j = 0; j < 24; j++) {
            acc[j * 3 + 0] += jrg[j] * s0;
            acc[j * 3 + 1] += jrg[j] * s1;
            acc[j * 3 + 2] += jrg[j] * s2;
        }
    }
#pragma unroll
    for (int o = 0; o < 72; o++) {
#pragma unroll
        for (int off = 1; off < 64; off <<= 1)
            acc[o] += __shfl_xor(acc[o], off);
    }
    if (lane == 0) {
#pragma unroll
        for (int o = 0; o < 72; o++) atomicAdd(&JS[row * 72 + o], acc[o]);
    }
}

// per-batch Rodrigues + chain (unchanged)
__global__ __launch_bounds__(64) void k_pose(const float* __restrict__ beta,
                                             const float* __restrict__ theta,
                                             const float* __restrict__ JS,
                                             float* __restrict__ coefT,
                                             float* __restrict__ Aw) {
    int n = blockIdx.x;
    int tid = threadIdx.x;
    __shared__ float Rs[24][9];
    __shared__ float Jl[24][3];
    __shared__ float G[24][12];

    if (tid < NJ) {
        int j = tid;
        float x = theta[n * 72 + j * 3 + 0];
        float y = theta[n * 72 + j * 3 + 1];
        float z = theta[n * 72 + j * 3 + 2];
        float ang = sqrtf(x * x + y * y + z * z + 1e-8f);
        float inv = 1.0f / ang;
        float rx = x * inv, ry = y * inv, rz = z * inv;
        float ct = cosf(ang), st = sinf(ang), oc = 1.0f - ct;
        float R[9];
        R[0] = ct + oc * rx * rx;  R[1] = -st * rz + oc * rx * ry; R[2] =  st * ry + oc * rx * rz;
        R[3] =  st * rz + oc * ry * rx; R[4] = ct + oc * ry * ry;  R[5] = -st * rx + oc * ry * rz;
        R[6] = -st * ry + oc * rz * rx; R[7] =  st * rx + oc * rz * ry; R[8] = ct + oc * rz * rz;
#pragma unroll
        for (int e = 0; e < 9; e++) Rs[j][e] = R[e];
        if (j >= 1) {
#pragma unroll
            for (int e = 0; e < 9; e++)
                coefT[(size_t)((j - 1) * 9 + e) * NB + n] =
                    R[e] - ((e == 0 || e == 4 || e == 8) ? 1.0f : 0.0f);
        }
    }
    if (tid < NBETA) coefT[(size_t)(NPOSE + tid) * NB + n] = beta[n * NBETA + tid];
    if (tid == 63)   coefT[(size_t)217 * NB + n] = 1.0f;
    __syncthreads();

    for (int idx = tid; idx < 72; idx += 64) {
        int j = idx / 3, a = idx - j * 3;
        float acc = JS[(NBETA * NJ + j) * 3 + a];
#pragma unroll
        for (int b = 0; b < NBETA; b++) acc += beta[n * NBETA + b] * JS[(b * NJ + j) * 3 + a];
        Jl[j][a] = acc;
    }
    __syncthreads();

    if (tid < 12) {
        int r = tid >> 2, cc = tid & 3;
        G[0][tid] = (cc < 3) ? Rs[0][r * 3 + cc] : Jl[0][r];
    }
    __syncthreads();

    const int PAR[24] = {0,0,0,0,1,2,3,4,5,6,7,8,9,9,9,12,13,14,16,17,18,19,20,21};
#pragma unroll
    for (int i = 1; i < NJ; i++) {
        int p = PAR[i];
        if (tid < 12) {
            int r = tid >> 2, cc = tid & 3;
            float g0 = G[p][r * 4 + 0], g1 = G[p][r * 4 + 1];
            float g2 = G[p][r * 4 + 2], g3 = G[p][r * 4 + 3];
            float val;
            if (cc < 3) {
                val = g0 * Rs[i][cc] + g1 * Rs[i][3 + cc] + g2 * Rs[i][6 + cc];
            } else {
                float t0 = Jl[i][0] - Jl[p][0];
                float t1 = Jl[i][1] - Jl[p][1];
                float t2 = Jl[i][2] - Jl[p][2];
                val = g0 * t0 + g1 * t1 + g2 * t2 + g3;
            }
            G[i][tid] = val;
        }
        __syncthreads();
    }

    for (int idx = tid; idx < 288; idx += 64) {
        int j = idx / 12, e = idx - j * 12;
        float val;
        if (e < 9) {
            int r = e / 3, cc = e - 3 * (e / 3);
            val = G[j][r * 4 + cc];
        } else {
            int r = e - 9;
            val = G[j][r * 4 + 3] -
                  (G[j][r * 4 + 0] * Jl[j][0] + G[j][r * 4 + 1] * Jl[j][1] +
                   G[j][r * 4 + 2] * Jl[j][2]);
        }
        Aw[(size_t)n * 288 + idx] = val;
    }
}

// LDS-free MFMA GEMM on fragment-packed operands. Block 128x128, 4 waves (2x2),
// wave 64x64 = 4x4 frags, 48 MFMA per k-step, split-K x24 + atomics.
__global__ __launch_bounds__(256) void k_gemmP(const unsigned short* __restrict__ APH,
                                               const unsigned short* __restrict__ APL,
                                               const unsigned short* __restrict__ BPH,
                                               const unsigned short* __restrict__ BPL,
                                               float* __restrict__ OUTB) {
    int bid = blockIdx.x;
    int mt = bid & 1;
    int nt = (bid >> 1) & 3;
    int a  = (bid >> 3) % 3;
    int ks = bid / 24;
    int tid = threadIdx.x;
    int lane = tid & 63, wv = tid >> 6;
    int wm = wv >> 1, wn = wv & 1;
    int lr = lane & 15, lc = lane >> 4;

    int rt0 = mt * 8 + wm * 4;
    int cf0 = nt * 8 + wn * 4;
    int vc0 = ks * KSTEPS;

    size_t oA[4], oB[4];
#pragma unroll
    for (int mi = 0; mi < 4; mi++)
        oA[mi] = (((size_t)(a * RTP + rt0 + mi) * NVC + vc0) * 64 + lane) * 8;
#pragma unroll
    for (int ni = 0; ni < 4; ni++)
        oB[ni] = (((size_t)(cf0 + ni) * NVC + vc0) * 64 + lane) * 8;

    f32x4 acc[4][4] = {};

    for (int s = 0; s < KSTEPS; ++s) {
        bf16x8 aH[4], aL[4], bH[4], bL[4];
#pragma unroll
        for (int mi = 0; mi < 4; mi++) {
            aH[mi] = *(const bf16x8*)(APH + oA[mi]);
            aL[mi] = *(const bf16x8*)(APL + oA[mi]);
        }
#pragma unroll
        for (int ni = 0; ni < 4; ni++) {
            bH[ni] = *(const bf16x8*)(BPH + oB[ni]);
            bL[ni] = *(const bf16x8*)(BPL + oB[ni]);
        }
#pragma unroll
        for (int mi = 0; mi < 4; mi++)
#pragma unroll
            for (int ni = 0; ni < 4; ni++) {
                acc[mi][ni] = __builtin_amdgcn_mfma_f32_16x16x32_bf16(aH[mi], bH[ni], acc[mi][ni], 0, 0, 0);
                acc[mi][ni] = __builtin_amdgcn_mfma_f32_16x16x32_bf16(aH[mi], bL[ni], acc[mi][ni], 0, 0, 0);
                acc[mi][ni] = __builtin_amdgcn_mfma_f32_16x16x32_bf16(aL[mi], bH[ni], acc[mi][ni], 0, 0, 0);
            }
#pragma unroll
        for (int mi = 0; mi < 4; mi++) oA[mi] += 512;
#pragma unroll
        for (int ni = 0; ni < 4; ni++) oB[ni] += 512;
    }

#pragma unroll
    for (int mi = 0; mi < 4; mi++) {
        int r0 = mt * 128 + wm * 64 + mi * 16 + lc * 4;
        if (r0 >= AR) continue;
#pragma unroll
        for (int ni = 0; ni < 4; ni++) {
            int c = nt * 128 + wn * 64 + ni * 16 + lr;
            if (c >= NKJ) continue;
#pragma unroll
            for (int q = 0; q < 4; ++q) {
                int r = r0 + q;
                if (r < AR)
                    atomicAdd(&OUTB[(size_t)r * NCOL + a * NKJ + c], acc[mi][ni][q]);
            }
        }
    }
}

// M[n][col] = sum_r coefT[r][n] * OUT[r][col]  (unchanged 32x64)
__global__ __launch_bounds__(256) void k_gemmM(const float* __restrict__ coefT,
                                               const float* __restrict__ OUTB,
                                               float* __restrict__ M) {
    int bid = blockIdx.x;
    int mt = bid & 31, nt = bid >> 5;
    int mb = mt * 32, nb = nt * 64;
    __shared__ float Cs[32][32];
    __shared__ float Bs[32][64];
    int tid = threadIdx.x;
    int tm = tid & 15, tn = tid >> 4;
    float acc[2][4] = {};
    for (int kb = 0; kb < KR; kb += 32) {
#pragma unroll
        for (int p = 0; p < 4; p++) {
            int idx = tid + p * 256;
            int kk = idx >> 5, nl = idx & 31;
            int r = kb + kk;
            Cs[kk][nl] = (r < KR) ? coefT[(size_t)r * NB + mb + nl] : 0.f;
        }
#pragma unroll
        for (int p = 0; p < 8; p++) {
            int idx = tid + p * 256;
            int kk = idx >> 6, m = idx & 63;
            int r = kb + kk;
            int col = nb + m;
            Bs[kk][m] = (r < KR && col < NCOL) ? OUTB[(size_t)r * NCOL + col] : 0.f;
        }
        __syncthreads();
#pragma unroll
        for (int kk = 0; kk < 32; kk++) {
            float2 cv = *(const float2*)&Cs[kk][tm * 2];
            float4 bv = *(const float4*)&Bs[kk][tn * 4];
            float cm[2] = {cv.x, cv.y};
            float bn[4] = {bv.x, bv.y, bv.z, bv.w};
#pragma unroll
            for (int i = 0; i < 2; i++)
#pragma unroll
                for (int j = 0; j < 4; j++) acc[i][j] += cm[i] * bn[j];
        }
        __syncthreads();
    }
#pragma unroll
    for (int i = 0; i < 2; i++) {
        int n = mb + tm * 2 + i;
#pragma unroll
        for (int j = 0; j < 4; j++) {
            int col = nb + tn * 4 + j;
            if (col < NCOL) M[(size_t)n * NCOL + col] = acc[i][j];
        }
    }
}

// joints: one thread per (n,k,a) — 3x parallelism of before, coalesced out
__global__ void k_joints(const float* __restrict__ M, const float* __restrict__ Aw,
                         const float* __restrict__ OUTB, float* __restrict__ out) {
    int idx = blockIdx.x * 256 + threadIdx.x;
    if (idx >= NB * NK * 3) return;
    int n = idx / (NK * 3);
    int rem = idx - n * (NK * 3);
    int k = rem / 3, a = rem - k * 3;
    const float* A = Aw + (size_t)n * 288;
    const float* Mn = M + (size_t)n * NCOL;
    float o = 0.f;
#pragma unroll
    for (int j = 0; j < NJ; j++) {
        int kj = k * NJ + j;
        const float* Aj = A + j * 12;
        o += Aj[a * 3 + 0] * Mn[kj]
           + Aj[a * 3 + 1] * Mn[NKJ + kj]
           + Aj[a * 3 + 2] * Mn[2 * NKJ + kj]
           + OUTB[(size_t)218 * NCOL + kj] * Aj[9 + a];
    }
    out[idx] = o;
}

extern "C" void kernel_launch(void* const* d_in, const int* in_sizes, int n_in,
                              void* d_out, int out_size, void* d_ws, size_t ws_size,
                              hipStream_t stream) {
    const float* beta  = (const float*)d_in[0];
    const float* theta = (const float*)d_in[1];
    const float* vt    = (const float*)d_in[2];
    const float* sd    = (const float*)d_in[3];
    const float* Jreg  = (const float*)d_in[4];
    const float* pd    = (const float*)d_in[5];
    const float* w     = (const float*)d_in[6];
    const float* jr    = (const float*)d_in[7];

    unsigned short* ush = (unsigned short*)d_ws;
    unsigned short* APH = ush;
    unsigned short* APL = APH + AP_PLANE;
    unsigned short* BPH = APL + AP_PLANE;
    unsigned short* BPL = BPH + BP_PLANE;
    float* fbase = (float*)(ush + USH_TOTAL);
    float* OUTB  = fbase;
    float* coefT = OUTB + SZ_OUT;
    float* Aw    = coefT + SZ_COEF;
    float* JS    = Aw + SZ_AW;
    float* M     = JS + SZ_JS;
    float* out   = (float*)d_out;

    hipMemsetAsync(OUTB, 0, (SZ_OUT + SZ_COEF + SZ_AW + SZ_JS) * sizeof(float), stream);
    k_at2<<<(256 * 864 + 255) / 256, 256, 0, stream>>>(pd, sd, vt, APH, APL);
    k_cw2<<<(512 * 864 + 255) / 256, 256, 0, stream>>>(jr, w, BPH, BPL);
    k_js2<<<11 * 7, 256, 0, stream>>>(Jreg, sd, vt, JS);
    k_pose<<<NB, 64, 0, stream>>>(beta, theta, JS, coefT, Aw);
    k_gemmP<<<2 * 4 * 3 * KSPLIT, 256, 0, stream>>>(APH, APL, BPH, BPL, OUTB);
    k_gemmM<<<32 * 22, 256, 0, stream>>>(coefT, OUTB, M);
    k_joints<<<(NB * NK * 3 + 255) / 256, 256, 0, stream>>>(M, Aw, OUTB, out);
}

// Round 8
// 226.559 us; speedup vs baseline: 1.1813x; 1.1813x over previous
//
#include <hip/hip_runtime.h>

#define NB 1024
#define NV 6890
#define VP 6912
#define NJ 24
#define NBETA 10
#define NPOSE 207
#define NK 19
#define NKJ 456
#define NCOL 1368
#define KR 218
#define AR 219
#define VSTR 20670
#define RTP 16        // row frags (256 rows padded)
#define NVC 216       // v chunks of 32
#define CFP 32        // col frags (512 cols padded)
#define KSPLIT 27
#define KSTEPS 8      // NVC/KSPLIT

typedef __attribute__((ext_vector_type(8))) short bf16x8;
typedef __attribute__((ext_vector_type(4))) float f32x4;

#define AP_PLANE ((size_t)3*RTP*NVC*64*8)   // 5,308,416 shorts
#define BP_PLANE ((size_t)CFP*NVC*64*8)     // 3,538,944 shorts
#define USH_TOTAL (2*AP_PLANE + 2*BP_PLANE)
#define SZ_OUT   ((size_t)AR*NCOL)
#define SZ_COEF  ((size_t)KR*NB)
#define SZ_AW    ((size_t)NB*288)
#define SZ_JS    (11ull*24*3)
#define SZ_M     ((size_t)NB*NCOL)

__device__ inline void bf_split(float x, unsigned short& h, unsigned short& l) {
    unsigned u = __float_as_uint(x);
    h = (unsigned short)(u >> 16);
    float hf = __uint_as_float((unsigned)h << 16);
    float lf = x - hf;
    l = (unsigned short)(__float_as_uint(lf) >> 16);
}

// A packed AP[a][rt][vc][lane=lh*16+rl][e]; wave writes contiguous 1KB fragments.
// thread: rl=tid&15 (row low), lh=(tid>>4)&3 (v sub), unit=(rt,vc) from blockIdx*4 + tid>>6.
__global__ __launch_bounds__(256) void k_at2(const float* __restrict__ pd,
                                             const float* __restrict__ sd,
                                             const float* __restrict__ vt,
                                             unsigned short* __restrict__ APH,
                                             unsigned short* __restrict__ APL) {
    int tid = threadIdx.x;
    int u = blockIdx.x * 4 + (tid >> 6);
    int rt = u / NVC, vc = u - rt * NVC;
    int rl = tid & 15, lh = (tid >> 4) & 3;
    int r = rt * 16 + rl;
    int v0 = (vc * 4 + lh) * 8;

    float f[24];
    if (r >= AR) {
#pragma unroll
        for (int i = 0; i < 24; i++) f[i] = 0.f;
    } else if (r == 218) {
#pragma unroll
        for (int i = 0; i < 24; i++) f[i] = (v0 + i / 3 < NV) ? 1.0f : 0.f;
    } else {
        const float* src = (r < NPOSE) ? (pd + (size_t)r * VSTR)
                         : (r < 217)   ? (sd + (size_t)(r - NPOSE) * VSTR)
                                       : vt;
        if (v0 + 8 <= NV) {
            const float2* p = (const float2*)(src + 3 * v0);
#pragma unroll
            for (int q = 0; q < 12; q++) {
                float2 t = p[q];
                f[2 * q] = t.x; f[2 * q + 1] = t.y;
            }
        } else {
#pragma unroll
            for (int i = 0; i < 24; i++)
                f[i] = (v0 + i / 3 < NV) ? src[3 * v0 + i] : 0.f;
        }
    }

    int lane = lh * 16 + rl;
#pragma unroll
    for (int a = 0; a < 3; a++) {
        union { unsigned short u16[8]; int4 v4; } H, L;
#pragma unroll
        for (int e = 0; e < 8; e++) bf_split(f[3 * e + a], H.u16[e], L.u16[e]);
        size_t off = (((size_t)(a * RTP + rt) * NVC + vc) * 64 + lane) * 8;
        *(int4*)&APH[off] = H.v4;
        *(int4*)&APL[off] = L.v4;
    }
}

// B packed BP[cf][vc][lane=lh*16+cl][e] = bf16(jr[v,k]*w[v,j]); coalesced writes.
__global__ __launch_bounds__(256) void k_cw2(const float* __restrict__ jr,
                                             const float* __restrict__ w,
                                             unsigned short* __restrict__ BPH,
                                             unsigned short* __restrict__ BPL) {
    int tid = threadIdx.x;
    int u = blockIdx.x * 4 + (tid >> 6);
    int cf = u / NVC, vc = u - cf * NVC;
    int cl = tid & 15, lh = (tid >> 4) & 3;
    int col = cf * 16 + cl;
    int v0 = (vc * 4 + lh) * 8;
    int k = col / NJ, j = col - k * NJ;
    bool okc = (col < NKJ);

    union { unsigned short u16[8]; int4 v4; } H, L;
#pragma unroll
    for (int e = 0; e < 8; e++) {
        int v = v0 + e;
        float val = (okc && v < NV) ? jr[v * NK + k] * w[v * NJ + j] : 0.f;
        bf_split(val, H.u16[e], L.u16[e]);
    }
    size_t off = (((size_t)cf * NVC + vc) * 64 + (lh * 16 + cl)) * 8;
    *(int4*)&BPH[off] = H.v4;
    *(int4*)&BPL[off] = L.v4;
}

// JS reduction (unchanged)
__global__ __launch_bounds__(256) void k_js2(const float* __restrict__ Jreg,
                                             const float* __restrict__ sd,
                                             const float* __restrict__ vt,
                                             float* __restrict__ JS) {
    int row = blockIdx.x % 11;
    int c   = blockIdx.x / 11;
    int tid = threadIdx.x;
    int lane = tid & 63;
    const float* src = (row < NBETA) ? (sd + (size_t)row * VSTR) : vt;

    float acc[72];
#pragma unroll
    for (int o = 0; o < 72; o++) acc[o] = 0.f;

    for (int iv = 0; iv < 4; ++iv) {
        int v = c * 1024 + iv * 256 + tid;
        float jrg[24];
        float s0 = 0.f, s1 = 0.f, s2 = 0.f;
        if (v < NV) {
#pragma unroll
            for (int q = 0; q < 6; q++) {
                float4 f = *(const float4*)&Jreg[v * NJ + q * 4];
                jrg[q * 4 + 0] = f.x; jrg[q * 4 + 1] = f.y;
                jrg[q * 4 + 2] = f.z; jrg[q * 4 + 3] = f.w;
            }
            s0 = src[3 * v]; s1 = src[3 * v + 1]; s2 = src[3 * v + 2];
        } else {
#pragma unroll
            for (int q = 0; q < 24; q++) jrg[q] = 0.f;
        }
#pragma unroll
        for (int j = 0; j < 24; j++) {
            acc[j * 3 + 0] += jrg[j] * s0;
            acc[j * 3 + 1] += jrg[j] * s1;
            acc[j * 3 + 2] += jrg[j] * s2;
        }
    }
#pragma unroll
    for (int o = 0; o < 72; o++) {
#pragma unroll
        for (int off = 1; off < 64; off <<= 1)
            acc[o] += __shfl_xor(acc[o], off);
    }
    if (lane == 0) {
#pragma unroll
        for (int o = 0; o < 72; o++) atomicAdd(&JS[row * 72 + o], acc[o]);
    }
}

// per-batch Rodrigues + chain (unchanged)
__global__ __launch_bounds__(64) void k_pose(const float* __restrict__ beta,
                                             const float* __restrict__ theta,
                                             const float* __restrict__ JS,
                                             float* __restrict__ coefT,
                                             float* __restrict__ Aw) {
    int n = blockIdx.x;
    int tid = threadIdx.x;
    __shared__ float Rs[24][9];
    __shared__ float Jl[24][3];
    __shared__ float G[24][12];

    if (tid < NJ) {
        int j = tid;
        float x = theta[n * 72 + j * 3 + 0];
        float y = theta[n * 72 + j * 3 + 1];
        float z = theta[n * 72 + j * 3 + 2];
        float ang = sqrtf(x * x + y * y + z * z + 1e-8f);
        float inv = 1.0f / ang;
        float rx = x * inv, ry = y * inv, rz = z * inv;
        float ct = cosf(ang), st = sinf(ang), oc = 1.0f - ct;
        float R[9];
        R[0] = ct + oc * rx * rx;  R[1] = -st * rz + oc * rx * ry; R[2] =  st * ry + oc * rx * rz;
        R[3] =  st * rz + oc * ry * rx; R[4] = ct + oc * ry * ry;  R[5] = -st * rx + oc * ry * rz;
        R[6] = -st * ry + oc * rz * rx; R[7] =  st * rx + oc * rz * ry; R[8] = ct + oc * rz * rz;
#pragma unroll
        for (int e = 0; e < 9; e++) Rs[j][e] = R[e];
        if (j >= 1) {
#pragma unroll
            for (int e = 0; e < 9; e++)
                coefT[(size_t)((j - 1) * 9 + e) * NB + n] =
                    R[e] - ((e == 0 || e == 4 || e == 8) ? 1.0f : 0.0f);
        }
    }
    if (tid < NBETA) coefT[(size_t)(NPOSE + tid) * NB + n] = beta[n * NBETA + tid];
    if (tid == 63)   coefT[(size_t)217 * NB + n] = 1.0f;
    __syncthreads();

    for (int idx = tid; idx < 72; idx += 64) {
        int j = idx / 3, a = idx - j * 3;
        float acc = JS[(NBETA * NJ + j) * 3 + a];
#pragma unroll
        for (int b = 0; b < NBETA; b++) acc += beta[n * NBETA + b] * JS[(b * NJ + j) * 3 + a];
        Jl[j][a] = acc;
    }
    __syncthreads();

    if (tid < 12) {
        int r = tid >> 2, cc = tid & 3;
        G[0][tid] = (cc < 3) ? Rs[0][r * 3 + cc] : Jl[0][r];
    }
    __syncthreads();

    const int PAR[24] = {0,0,0,0,1,2,3,4,5,6,7,8,9,9,9,12,13,14,16,17,18,19,20,21};
#pragma unroll
    for (int i = 1; i < NJ; i++) {
        int p = PAR[i];
        if (tid < 12) {
            int r = tid >> 2, cc = tid & 3;
            float g0 = G[p][r * 4 + 0], g1 = G[p][r * 4 + 1];
            float g2 = G[p][r * 4 + 2], g3 = G[p][r * 4 + 3];
            float val;
            if (cc < 3) {
                val = g0 * Rs[i][cc] + g1 * Rs[i][3 + cc] + g2 * Rs[i][6 + cc];
            } else {
                float t0 = Jl[i][0] - Jl[p][0];
                float t1 = Jl[i][1] - Jl[p][1];
                float t2 = Jl[i][2] - Jl[p][2];
                val = g0 * t0 + g1 * t1 + g2 * t2 + g3;
            }
            G[i][tid] = val;
        }
        __syncthreads();
    }

    for (int idx = tid; idx < 288; idx += 64) {
        int j = idx / 12, e = idx - j * 12;
        float val;
        if (e < 9) {
            int r = e / 3, cc = e - 3 * (e / 3);
            val = G[j][r * 4 + cc];
        } else {
            int r = e - 9;
            val = G[j][r * 4 + 3] -
                  (G[j][r * 4 + 0] * Jl[j][0] + G[j][r * 4 + 1] * Jl[j][1] +
                   G[j][r * 4 + 2] * Jl[j][2]);
        }
        Aw[(size_t)n * 288 + idx] = val;
    }
}

// MFMA GEMM, 128x64 tiles, KSPLIT=27 (1296 blocks), XCD-chunked swizzle (nt innermost),
// LDS-free on fragment-packed planes, launch_bounds caps VGPR<=128 for 4 waves/SIMD.
__global__ __launch_bounds__(256, 4) void k_gemmP(const unsigned short* __restrict__ APH,
                                                  const unsigned short* __restrict__ APL,
                                                  const unsigned short* __restrict__ BPH,
                                                  const unsigned short* __restrict__ BPL,
                                                  float* __restrict__ OUTB) {
    int bid = blockIdx.x;
    int logical = (bid & 7) * 162 + (bid >> 3);   // XCD-chunked: 1296 = 8*162
    int mt = logical / 648;
    int r1 = logical - mt * 648;
    int a  = r1 / 216;
    int r2 = r1 - a * 216;
    int ks = r2 >> 3;
    int nt = r2 & 7;

    int tid = threadIdx.x;
    int lane = tid & 63, wv = tid >> 6;
    int wm = wv >> 1, wn = wv & 1;
    int lr = lane & 15, lc = lane >> 4;

    int vc0 = ks * KSTEPS;
    int oA[4], oB[2];
#pragma unroll
    for (int mi = 0; mi < 4; mi++)
        oA[mi] = (((a * RTP + mt * 8 + wm * 4 + mi) * NVC + vc0) * 64 + lane) * 8;
#pragma unroll
    for (int ni = 0; ni < 2; ni++)
        oB[ni] = (((nt * 4 + wn * 2 + ni) * NVC + vc0) * 64 + lane) * 8;

    f32x4 acc[4][2] = {};

#pragma unroll
    for (int s = 0; s < KSTEPS; ++s) {
        bf16x8 aH[4], aL[4], bH[2], bL[2];
#pragma unroll
        for (int mi = 0; mi < 4; mi++) {
            aH[mi] = *(const bf16x8*)(APH + oA[mi]);
            aL[mi] = *(const bf16x8*)(APL + oA[mi]);
            oA[mi] += 512;
        }
#pragma unroll
        for (int ni = 0; ni < 2; ni++) {
            bH[ni] = *(const bf16x8*)(BPH + oB[ni]);
            bL[ni] = *(const bf16x8*)(BPL + oB[ni]);
            oB[ni] += 512;
        }
#pragma unroll
        for (int mi = 0; mi < 4; mi++)
#pragma unroll
            for (int ni = 0; ni < 2; ni++) {
                acc[mi][ni] = __builtin_amdgcn_mfma_f32_16x16x32_bf16(aH[mi], bH[ni], acc[mi][ni], 0, 0, 0);
                acc[mi][ni] = __builtin_amdgcn_mfma_f32_16x16x32_bf16(aH[mi], bL[ni], acc[mi][ni], 0, 0, 0);
                acc[mi][ni] = __builtin_amdgcn_mfma_f32_16x16x32_bf16(aL[mi], bH[ni], acc[mi][ni], 0, 0, 0);
            }
    }

#pragma unroll
    for (int mi = 0; mi < 4; mi++) {
        int r0 = mt * 128 + wm * 64 + mi * 16 + lc * 4;
        if (r0 >= AR) continue;
#pragma unroll
        for (int ni = 0; ni < 2; ni++) {
            int c = nt * 64 + wn * 32 + ni * 16 + lr;
            if (c >= NKJ) continue;
#pragma unroll
            for (int q = 0; q < 4; ++q) {
                int r = r0 + q;
                if (r < AR)
                    atomicAdd(&OUTB[(size_t)r * NCOL + a * NKJ + c], acc[mi][ni][q]);
            }
        }
    }
}

// M = coefT^T @ OUT  (unchanged 32x64)
__global__ __launch_bounds__(256) void k_gemmM(const float* __restrict__ coefT,
                                               const float* __restrict__ OUTB,
                                               float* __restrict__ M) {
    int bid = blockIdx.x;
    int mt = bid & 31, nt = bid >> 5;
    int mb = mt * 32, nb = nt * 64;
    __shared__ float Cs[32][32];
    __shared__ float Bs[32][64];
    int tid = threadIdx.x;
    int tm = tid & 15, tn = tid >> 4;
    float acc[2][4] = {};
    for (int kb = 0; kb < KR; kb += 32) {
#pragma unroll
        for (int p = 0; p < 4; p++) {
            int idx = tid + p * 256;
            int kk = idx >> 5, nl = idx & 31;
            int r = kb + kk;
            Cs[kk][nl] = (r < KR) ? coefT[(size_t)r * NB + mb + nl] : 0.f;
        }
#pragma unroll
        for (int p = 0; p < 8; p++) {
            int idx = tid + p * 256;
            int kk = idx >> 6, m = idx & 63;
            int r = kb + kk;
            int col = nb + m;
            Bs[kk][m] = (r < KR && col < NCOL) ? OUTB[(size_t)r * NCOL + col] : 0.f;
        }
        __syncthreads();
#pragma unroll
        for (int kk = 0; kk < 32; kk++) {
            float2 cv = *(const float2*)&Cs[kk][tm * 2];
            float4 bv = *(const float4*)&Bs[kk][tn * 4];
            float cm[2] = {cv.x, cv.y};
            float bn[4] = {bv.x, bv.y, bv.z, bv.w};
#pragma unroll
            for (int i = 0; i < 2; i++)
#pragma unroll
                for (int j = 0; j < 4; j++) acc[i][j] += cm[i] * bn[j];
        }
        __syncthreads();
    }
#pragma unroll
    for (int i = 0; i < 2; i++) {
        int n = mb + tm * 2 + i;
#pragma unroll
        for (int j = 0; j < 4; j++) {
            int col = nb + tn * 4 + j;
            if (col < NCOL) M[(size_t)n * NCOL + col] = acc[i][j];
        }
    }
}

// joints: one thread per (n,k,a)
__global__ void k_joints(const float* __restrict__ M, const float* __restrict__ Aw,
                         const float* __restrict__ OUTB, float* __restrict__ out) {
    int idx = blockIdx.x * 256 + threadIdx.x;
    if (idx >= NB * NK * 3) return;
    int n = idx / (NK * 3);
    int rem = idx - n * (NK * 3);
    int k = rem / 3, a = rem - k * 3;
    const float* A = Aw + (size_t)n * 288;
    const float* Mn = M + (size_t)n * NCOL;
    float o = 0.f;
#pragma unroll
    for (int j = 0; j < NJ; j++) {
        int kj = k * NJ + j;
        const float* Aj = A + j * 12;
        o += Aj[a * 3 + 0] * Mn[kj]
           + Aj[a * 3 + 1] * Mn[NKJ + kj]
           + Aj[a * 3 + 2] * Mn[2 * NKJ + kj]
           + OUTB[(size_t)218 * NCOL + kj] * Aj[9 + a];
    }
    out[idx] = o;
}

extern "C" void kernel_launch(void* const* d_in, const int* in_sizes, int n_in,
                              void* d_out, int out_size, void* d_ws, size_t ws_size,
                              hipStream_t stream) {
    const float* beta  = (const float*)d_in[0];
    const float* theta = (const float*)d_in[1];
    const float* vt    = (const float*)d_in[2];
    const float* sd    = (const float*)d_in[3];
    const float* Jreg  = (const float*)d_in[4];
    const float* pd    = (const float*)d_in[5];
    const float* w     = (const float*)d_in[6];
    const float* jr    = (const float*)d_in[7];

    unsigned short* ush = (unsigned short*)d_ws;
    unsigned short* APH = ush;
    unsigned short* APL = APH + AP_PLANE;
    unsigned short* BPH = APL + AP_PLANE;
    unsigned short* BPL = BPH + BP_PLANE;
    float* fbase = (float*)(ush + USH_TOTAL);
    float* OUTB  = fbase;
    float* coefT = OUTB + SZ_OUT;
    float* Aw    = coefT + SZ_COEF;
    float* JS    = Aw + SZ_AW;
    float* M     = JS + SZ_JS;
    float* out   = (float*)d_out;

    hipMemsetAsync(OUTB, 0, (SZ_OUT + SZ_COEF + SZ_AW + SZ_JS) * sizeof(float), stream);
    k_at2<<<16 * NVC / 4, 256, 0, stream>>>(pd, sd, vt, APH, APL);
    k_cw2<<<CFP * NVC / 4, 256, 0, stream>>>(jr, w, BPH, BPL);
    k_js2<<<11 * 7, 256, 0, stream>>>(Jreg, sd, vt, JS);
    k_pose<<<NB, 64, 0, stream>>>(beta, theta, JS, coefT, Aw);
    k_gemmP<<<2 * 8 * 3 * KSPLIT, 256, 0, stream>>>(APH, APL, BPH, BPL, OUTB);
    k_gemmM<<<32 * 22, 256, 0, stream>>>(coefT, OUTB, M);
    k_joints<<<(NB * NK * 3 + 255) / 256, 256, 0, stream>>>(M, Aw, OUTB, out);
}

// Round 9
// 209.110 us; speedup vs baseline: 1.2799x; 1.0834x over previous
//
#include <hip/hip_runtime.h>

#define NB 1024
#define NV 6890
#define VP 6912
#define NJ 24
#define NBETA 10
#define NPOSE 207
#define NK 19
#define NKJ 456
#define NCOL 1368
#define KR 218
#define AR 219
#define VSTR 20670
#define RTP 16        // row frags (256 rows padded)
#define NVC 216       // v chunks of 32
#define CFP 32        // col frags (512 cols padded)
#define KSPLIT 27
#define KSTEPS 8      // NVC/KSPLIT

typedef __attribute__((ext_vector_type(8))) short bf16x8;
typedef __attribute__((ext_vector_type(4))) float f32x4;

#define AP_PLANE ((size_t)3*RTP*NVC*64*8)   // 5,308,416 shorts
#define BP_PLANE ((size_t)CFP*NVC*64*8)     // 3,538,944 shorts
#define USH_TOTAL (2*AP_PLANE + 2*BP_PLANE)
#define SZ_OUT   ((size_t)AR*NCOL)
#define SZ_COEF  ((size_t)KR*NB)
#define SZ_AW    ((size_t)NB*288)
#define SZ_JS    (11ull*24*3)
#define SZ_M     ((size_t)NB*NCOL)

__device__ inline void bf_split(float x, unsigned short& h, unsigned short& l) {
    unsigned u = __float_as_uint(x);
    h = (unsigned short)(u >> 16);
    float hf = __uint_as_float((unsigned)h << 16);
    float lf = x - hf;
    l = (unsigned short)(__float_as_uint(lf) >> 16);
}

// A packed AP[a][rt][vc][lane=lh*16+rl][e]; wave writes contiguous 1KB fragments.
__global__ __launch_bounds__(256) void k_at2(const float* __restrict__ pd,
                                             const float* __restrict__ sd,
                                             const float* __restrict__ vt,
                                             unsigned short* __restrict__ APH,
                                             unsigned short* __restrict__ APL) {
    int tid = threadIdx.x;
    int u = blockIdx.x * 4 + (tid >> 6);
    int rt = u / NVC, vc = u - rt * NVC;
    int rl = tid & 15, lh = (tid >> 4) & 3;
    int r = rt * 16 + rl;
    int v0 = (vc * 4 + lh) * 8;

    float f[24];
    if (r >= AR) {
#pragma unroll
        for (int i = 0; i < 24; i++) f[i] = 0.f;
    } else if (r == 218) {
#pragma unroll
        for (int i = 0; i < 24; i++) f[i] = (v0 + i / 3 < NV) ? 1.0f : 0.f;
    } else {
        const float* src = (r < NPOSE) ? (pd + (size_t)r * VSTR)
                         : (r < 217)   ? (sd + (size_t)(r - NPOSE) * VSTR)
                                       : vt;
        if (v0 + 8 <= NV) {
            const float2* p = (const float2*)(src + 3 * v0);
#pragma unroll
            for (int q = 0; q < 12; q++) {
                float2 t = p[q];
                f[2 * q] = t.x; f[2 * q + 1] = t.y;
            }
        } else {
#pragma unroll
            for (int i = 0; i < 24; i++)
                f[i] = (v0 + i / 3 < NV) ? src[3 * v0 + i] : 0.f;
        }
    }

    int lane = lh * 16 + rl;
#pragma unroll
    for (int a = 0; a < 3; a++) {
        union { unsigned short u16[8]; int4 v4; } H, L;
#pragma unroll
        for (int e = 0; e < 8; e++) bf_split(f[3 * e + a], H.u16[e], L.u16[e]);
        size_t off = (((size_t)(a * RTP + rt) * NVC + vc) * 64 + lane) * 8;
        *(int4*)&APH[off] = H.v4;
        *(int4*)&APL[off] = L.v4;
    }
}

// B packed BP[cf][vc][lane=lh*16+cl][e] = bf16(jr[v,k]*w[v,j]); coalesced writes.
__global__ __launch_bounds__(256) void k_cw2(const float* __restrict__ jr,
                                             const float* __restrict__ w,
                                             unsigned short* __restrict__ BPH,
                                             unsigned short* __restrict__ BPL) {
    int tid = threadIdx.x;
    int u = blockIdx.x * 4 + (tid >> 6);
    int cf = u / NVC, vc = u - cf * NVC;
    int cl = tid & 15, lh = (tid >> 4) & 3;
    int col = cf * 16 + cl;
    int v0 = (vc * 4 + lh) * 8;
    int k = col / NJ, j = col - k * NJ;
    bool okc = (col < NKJ);

    union { unsigned short u16[8]; int4 v4; } H, L;
#pragma unroll
    for (int e = 0; e < 8; e++) {
        int v = v0 + e;
        float val = (okc && v < NV) ? jr[v * NK + k] * w[v * NJ + j] : 0.f;
        bf_split(val, H.u16[e], L.u16[e]);
    }
    size_t off = (((size_t)cf * NVC + vc) * 64 + (lh * 16 + cl)) * 8;
    *(int4*)&BPH[off] = H.v4;
    *(int4*)&BPL[off] = L.v4;
}

// JS reduction (unchanged)
__global__ __launch_bounds__(256) void k_js2(const float* __restrict__ Jreg,
                                             const float* __restrict__ sd,
                                             const float* __restrict__ vt,
                                             float* __restrict__ JS) {
    int row = blockIdx.x % 11;
    int c   = blockIdx.x / 11;
    int tid = threadIdx.x;
    int lane = tid & 63;
    const float* src = (row < NBETA) ? (sd + (size_t)row * VSTR) : vt;

    float acc[72];
#pragma unroll
    for (int o = 0; o < 72; o++) acc[o] = 0.f;

    for (int iv = 0; iv < 4; ++iv) {
        int v = c * 1024 + iv * 256 + tid;
        float jrg[24];
        float s0 = 0.f, s1 = 0.f, s2 = 0.f;
        if (v < NV) {
#pragma unroll
            for (int q = 0; q < 6; q++) {
                float4 f = *(const float4*)&Jreg[v * NJ + q * 4];
                jrg[q * 4 + 0] = f.x; jrg[q * 4 + 1] = f.y;
                jrg[q * 4 + 2] = f.z; jrg[q * 4 + 3] = f.w;
            }
            s0 = src[3 * v]; s1 = src[3 * v + 1]; s2 = src[3 * v + 2];
        } else {
#pragma unroll
            for (int q = 0; q < 24; q++) jrg[q] = 0.f;
        }
#pragma unroll
        for (int j = 0; j < 24; j++) {
            acc[j * 3 + 0] += jrg[j] * s0;
            acc[j * 3 + 1] += jrg[j] * s1;
            acc[j * 3 + 2] += jrg[j] * s2;
        }
    }
#pragma unroll
    for (int o = 0; o < 72; o++) {
#pragma unroll
        for (int off = 1; off < 64; off <<= 1)
            acc[o] += __shfl_xor(acc[o], off);
    }
    if (lane == 0) {
#pragma unroll
        for (int o = 0; o < 72; o++) atomicAdd(&JS[row * 72 + o], acc[o]);
    }
}

// per-batch Rodrigues + chain (unchanged)
__global__ __launch_bounds__(64) void k_pose(const float* __restrict__ beta,
                                             const float* __restrict__ theta,
                                             const float* __restrict__ JS,
                                             float* __restrict__ coefT,
                                             float* __restrict__ Aw) {
    int n = blockIdx.x;
    int tid = threadIdx.x;
    __shared__ float Rs[24][9];
    __shared__ float Jl[24][3];
    __shared__ float G[24][12];

    if (tid < NJ) {
        int j = tid;
        float x = theta[n * 72 + j * 3 + 0];
        float y = theta[n * 72 + j * 3 + 1];
        float z = theta[n * 72 + j * 3 + 2];
        float ang = sqrtf(x * x + y * y + z * z + 1e-8f);
        float inv = 1.0f / ang;
        float rx = x * inv, ry = y * inv, rz = z * inv;
        float ct = cosf(ang), st = sinf(ang), oc = 1.0f - ct;
        float R[9];
        R[0] = ct + oc * rx * rx;  R[1] = -st * rz + oc * rx * ry; R[2] =  st * ry + oc * rx * rz;
        R[3] =  st * rz + oc * ry * rx; R[4] = ct + oc * ry * ry;  R[5] = -st * rx + oc * ry * rz;
        R[6] = -st * ry + oc * rz * rx; R[7] =  st * rx + oc * rz * ry; R[8] = ct + oc * rz * rz;
#pragma unroll
        for (int e = 0; e < 9; e++) Rs[j][e] = R[e];
        if (j >= 1) {
#pragma unroll
            for (int e = 0; e < 9; e++)
                coefT[(size_t)((j - 1) * 9 + e) * NB + n] =
                    R[e] - ((e == 0 || e == 4 || e == 8) ? 1.0f : 0.0f);
        }
    }
    if (tid < NBETA) coefT[(size_t)(NPOSE + tid) * NB + n] = beta[n * NBETA + tid];
    if (tid == 63)   coefT[(size_t)217 * NB + n] = 1.0f;
    __syncthreads();

    for (int idx = tid; idx < 72; idx += 64) {
        int j = idx / 3, a = idx - j * 3;
        float acc = JS[(NBETA * NJ + j) * 3 + a];
#pragma unroll
        for (int b = 0; b < NBETA; b++) acc += beta[n * NBETA + b] * JS[(b * NJ + j) * 3 + a];
        Jl[j][a] = acc;
    }
    __syncthreads();

    if (tid < 12) {
        int r = tid >> 2, cc = tid & 3;
        G[0][tid] = (cc < 3) ? Rs[0][r * 3 + cc] : Jl[0][r];
    }
    __syncthreads();

    const int PAR[24] = {0,0,0,0,1,2,3,4,5,6,7,8,9,9,9,12,13,14,16,17,18,19,20,21};
#pragma unroll
    for (int i = 1; i < NJ; i++) {
        int p = PAR[i];
        if (tid < 12) {
            int r = tid >> 2, cc = tid & 3;
            float g0 = G[p][r * 4 + 0], g1 = G[p][r * 4 + 1];
            float g2 = G[p][r * 4 + 2], g3 = G[p][r * 4 + 3];
            float val;
            if (cc < 3) {
                val = g0 * Rs[i][cc] + g1 * Rs[i][3 + cc] + g2 * Rs[i][6 + cc];
            } else {
                float t0 = Jl[i][0] - Jl[p][0];
                float t1 = Jl[i][1] - Jl[p][1];
                float t2 = Jl[i][2] - Jl[p][2];
                val = g0 * t0 + g1 * t1 + g2 * t2 + g3;
            }
            G[i][tid] = val;
        }
        __syncthreads();
    }

    for (int idx = tid; idx < 288; idx += 64) {
        int j = idx / 12, e = idx - j * 12;
        float val;
        if (e < 9) {
            int r = e / 3, cc = e - 3 * (e / 3);
            val = G[j][r * 4 + cc];
        } else {
            int r = e - 9;
            val = G[j][r * 4 + 3] -
                  (G[j][r * 4 + 0] * Jl[j][0] + G[j][r * 4 + 1] * Jl[j][1] +
                   G[j][r * 4 + 2] * Jl[j][2]);
        }
        Aw[(size_t)n * 288 + idx] = val;
    }
}

// MFMA GEMM, 128x64 tiles, KSPLIT=27 (1296 blocks).
// ks-major XCD chunks (each XCD spans ~3.4 ks slices -> ~4.4MB working set ~ L2),
// register double-buffer: load k+1 while MFMA k.
#define LOADF(S, AH, AL, BH, BL) do {                                   \
    int _o = (S) * 512;                                                  \
    _Pragma("unroll") for (int mi = 0; mi < 4; mi++) {                   \
        AH[mi] = *(const bf16x8*)(APH + oA[mi] + _o);                    \
        AL[mi] = *(const bf16x8*)(APL + oA[mi] + _o); }                  \
    _Pragma("unroll") for (int ni = 0; ni < 2; ni++) {                   \
        BH[ni] = *(const bf16x8*)(BPH + oB[ni] + _o);                    \
        BL[ni] = *(const bf16x8*)(BPL + oB[ni] + _o); }                  \
} while (0)

#define MFMAF(AH, AL, BH, BL) do {                                       \
    _Pragma("unroll") for (int mi = 0; mi < 4; mi++)                     \
    _Pragma("unroll") for (int ni = 0; ni < 2; ni++) {                   \
        acc[mi][ni] = __builtin_amdgcn_mfma_f32_16x16x32_bf16(AH[mi], BH[ni], acc[mi][ni], 0, 0, 0); \
        acc[mi][ni] = __builtin_amdgcn_mfma_f32_16x16x32_bf16(AH[mi], BL[ni], acc[mi][ni], 0, 0, 0); \
        acc[mi][ni] = __builtin_amdgcn_mfma_f32_16x16x32_bf16(AL[mi], BH[ni], acc[mi][ni], 0, 0, 0); } \
} while (0)

__global__ __launch_bounds__(256) void k_gemmP(const unsigned short* __restrict__ APH,
                                               const unsigned short* __restrict__ APL,
                                               const unsigned short* __restrict__ BPH,
                                               const unsigned short* __restrict__ BPL,
                                               float* __restrict__ OUTB) {
    int bid = blockIdx.x;
    int logical = (bid & 7) * 162 + (bid >> 3);   // 1296 = 8 XCD chunks of 162
    int ks = logical / 48;                        // ks-major within chunk
    int rem = logical - ks * 48;
    int a  = rem >> 4;
    int mt = (rem >> 3) & 1;
    int nt = rem & 7;

    int tid = threadIdx.x;
    int lane = tid & 63, wv = tid >> 6;
    int wm = wv >> 1, wn = wv & 1;
    int lr = lane & 15, lc = lane >> 4;

    int vc0 = ks * KSTEPS;
    int oA[4], oB[2];
#pragma unroll
    for (int mi = 0; mi < 4; mi++)
        oA[mi] = (((a * RTP + mt * 8 + wm * 4 + mi) * NVC + vc0) * 64 + lane) * 8;
#pragma unroll
    for (int ni = 0; ni < 2; ni++)
        oB[ni] = (((nt * 4 + wn * 2 + ni) * NVC + vc0) * 64 + lane) * 8;

    f32x4 acc[4][2] = {};
    bf16x8 aH0[4], aL0[4], bH0[2], bL0[2];
    bf16x8 aH1[4], aL1[4], bH1[2], bL1[2];

    LOADF(0, aH0, aL0, bH0, bL0);
#pragma unroll
    for (int s = 0; s < KSTEPS; ++s) {
        if ((s & 1) == 0) {
            if (s + 1 < KSTEPS) LOADF(s + 1, aH1, aL1, bH1, bL1);
            MFMAF(aH0, aL0, bH0, bL0);
        } else {
            if (s + 1 < KSTEPS) LOADF(s + 1, aH0, aL0, bH0, bL0);
            MFMAF(aH1, aL1, bH1, bL1);
        }
    }

#pragma unroll
    for (int mi = 0; mi < 4; mi++) {
        int r0 = mt * 128 + wm * 64 + mi * 16 + lc * 4;
        if (r0 >= AR) continue;
#pragma unroll
        for (int ni = 0; ni < 2; ni++) {
            int c = nt * 64 + wn * 32 + ni * 16 + lr;
            if (c >= NKJ) continue;
#pragma unroll
            for (int q = 0; q < 4; ++q) {
                int r = r0 + q;
                if (r < AR)
                    atomicAdd(&OUTB[(size_t)r * NCOL + a * NKJ + c], acc[mi][ni][q]);
            }
        }
    }
}

// M = coefT^T @ OUT, 32x64 tiles, LDS double-buffer: load kb+1 while computing kb.
__global__ __launch_bounds__(256) void k_gemmM(const float* __restrict__ coefT,
                                               const float* __restrict__ OUTB,
                                               float* __restrict__ M) {
    int bid = blockIdx.x;
    int mt = bid & 31, nt = bid >> 5;
    int mb = mt * 32, nb = nt * 64;
    __shared__ float Cs[2][32][32];
    __shared__ float Bs[2][32][64];
    int tid = threadIdx.x;
    int tm = tid & 15, tn = tid >> 4;

    float rc[4], rb[8];
#define LOADM(T) do {                                                    \
    int _kb = (T) * 32;                                                  \
    _Pragma("unroll") for (int p = 0; p < 4; p++) {                      \
        int idx = tid + p * 256;                                         \
        int kk = idx >> 5, nl = idx & 31;                                \
        int r = _kb + kk;                                                \
        rc[p] = (r < KR) ? coefT[(size_t)r * NB + mb + nl] : 0.f; }      \
    _Pragma("unroll") for (int p = 0; p < 8; p++) {                      \
        int idx = tid + p * 256;                                         \
        int kk = idx >> 6, m = idx & 63;                                 \
        int r = _kb + kk;                                                \
        int col = nb + m;                                                \
        rb[p] = (r < KR && col < NCOL) ? OUTB[(size_t)r * NCOL + col] : 0.f; } \
} while (0)

    LOADM(0);
    float acc[2][4] = {};
    int cur = 0;
    for (int t = 0; t < 7; ++t) {
#pragma unroll
        for (int p = 0; p < 4; p++) {
            int idx = tid + p * 256;
            Cs[cur][idx >> 5][idx & 31] = rc[p];
        }
#pragma unroll
        for (int p = 0; p < 8; p++) {
            int idx = tid + p * 256;
            Bs[cur][idx >> 6][idx & 63] = rb[p];
        }
        __syncthreads();
        if (t < 6) LOADM(t + 1);
#pragma unroll
        for (int kk = 0; kk < 32; kk++) {
            float2 cv = *(const float2*)&Cs[cur][kk][tm * 2];
            float4 bv = *(const float4*)&Bs[cur][kk][tn * 4];
            float cm[2] = {cv.x, cv.y};
            float bn[4] = {bv.x, bv.y, bv.z, bv.w};
#pragma unroll
            for (int i = 0; i < 2; i++)
#pragma unroll
                for (int j = 0; j < 4; j++) acc[i][j] += cm[i] * bn[j];
        }
        __syncthreads();
        cur ^= 1;
    }
#pragma unroll
    for (int i = 0; i < 2; i++) {
        int n = mb + tm * 2 + i;
#pragma unroll
        for (int j = 0; j < 4; j++) {
            int col = nb + tn * 4 + j;
            if (col < NCOL) M[(size_t)n * NCOL + col] = acc[i][j];
        }
    }
}

// joints: one thread per (n,k,a)
__global__ void k_joints(const float* __restrict__ M, const float* __restrict__ Aw,
                         const float* __restrict__ OUTB, float* __restrict__ out) {
    int idx = blockIdx.x * 256 + threadIdx.x;
    if (idx >= NB * NK * 3) return;
    int n = idx / (NK * 3);
    int rem = idx - n * (NK * 3);
    int k = rem / 3, a = rem - k * 3;
    const float* A = Aw + (size_t)n * 288;
    const float* Mn = M + (size_t)n * NCOL;
    float o = 0.f;
#pragma unroll
    for (int j = 0; j < NJ; j++) {
        int kj = k * NJ + j;
        const float* Aj = A + j * 12;
        o += Aj[a * 3 + 0] * Mn[kj]
           + Aj[a * 3 + 1] * Mn[NKJ + kj]
           + Aj[a * 3 + 2] * Mn[2 * NKJ + kj]
           + OUTB[(size_t)218 * NCOL + kj] * Aj[9 + a];
    }
    out[idx] = o;
}

extern "C" void kernel_launch(void* const* d_in, const int* in_sizes, int n_in,
                              void* d_out, int out_size, void* d_ws, size_t ws_size,
                              hipStream_t stream) {
    const float* beta  = (const float*)d_in[0];
    const float* theta = (const float*)d_in[1];
    const float* vt    = (const float*)d_in[2];
    const float* sd    = (const float*)d_in[3];
    const float* Jreg  = (const float*)d_in[4];
    const float* pd    = (const float*)d_in[5];
    const float* w     = (const float*)d_in[6];
    const float* jr    = (const float*)d_in[7];

    unsigned short* ush = (unsigned short*)d_ws;
    unsigned short* APH = ush;
    unsigned short* APL = APH + AP_PLANE;
    unsigned short* BPH = APL + AP_PLANE;
    unsigned short* BPL = BPH + BP_PLANE;
    float* fbase = (float*)(ush + USH_TOTAL);
    float* OUTB  = fbase;
    float* coefT = OUTB + SZ_OUT;
    float* Aw    = coefT + SZ_COEF;
    float* JS    = Aw + SZ_AW;
    float* M     = JS + SZ_JS;
    float* out   = (float*)d_out;

    hipMemsetAsync(OUTB, 0, (SZ_OUT + SZ_COEF + SZ_AW + SZ_JS) * sizeof(float), stream);
    k_at2<<<16 * NVC / 4, 256, 0, stream>>>(pd, sd, vt, APH, APL);
    k_cw2<<<CFP * NVC / 4, 256, 0, stream>>>(jr, w, BPH, BPL);
    k_js2<<<11 * 7, 256, 0, stream>>>(Jreg, sd, vt, JS);
    k_pose<<<NB, 64, 0, stream>>>(beta, theta, JS, coefT, Aw);
    k_gemmP<<<2 * 8 * 3 * KSPLIT, 256, 0, stream>>>(APH, APL, BPH, BPL, OUTB);
    k_gemmM<<<32 * 22, 256, 0, stream>>>(coefT, OUTB, M);
    k_joints<<<(NB * NK * 3 + 255) / 256, 256, 0, stream>>>(M, Aw, OUTB, out);
}

// Round 10
// 186.946 us; speedup vs baseline: 1.4316x; 1.1186x over previous
//
#include <hip/hip_runtime.h>

#define NB 1024
#define NV 6890
#define VP 6912
#define NJ 24
#define NBETA 10
#define NPOSE 207
#define NK 19
#define NKJ 456
#define NCOL 1368
#define KR 218
#define AR 219
#define VSTR 20670
#define RTP 16        // row frags (256 rows padded)
#define NVC 216       // v chunks of 32
#define CFP 32        // col frags (512 cols padded)
#define KSPLIT 12
#define KSTEPS 18     // NVC/KSPLIT

typedef __attribute__((ext_vector_type(8))) short bf16x8;
typedef __attribute__((ext_vector_type(4))) float f32x4;

#define AP_PLANE ((size_t)3*RTP*NVC*64*8)   // 5,308,416 shorts
#define BP_PLANE ((size_t)CFP*NVC*64*8)     // 3,538,944 shorts
#define USH_TOTAL (2*AP_PLANE + 2*BP_PLANE)
#define SZ_OUT   ((size_t)AR*NCOL)
#define SZ_COEF  ((size_t)KR*NB)
#define SZ_AW    ((size_t)NB*288)
#define SZ_JS    (11ull*24*3)
#define SZ_M     ((size_t)NB*NCOL)

__device__ inline void bf_split(float x, unsigned short& h, unsigned short& l) {
    unsigned u = __float_as_uint(x);
    h = (unsigned short)(u >> 16);
    float hf = __uint_as_float((unsigned)h << 16);
    float lf = x - hf;
    l = (unsigned short)(__float_as_uint(lf) >> 16);
}

// A packed AP[a][rt][vc][lane=lh*16+rl][e]; wave writes contiguous 1KB fragments.
__global__ __launch_bounds__(256) void k_at2(const float* __restrict__ pd,
                                             const float* __restrict__ sd,
                                             const float* __restrict__ vt,
                                             unsigned short* __restrict__ APH,
                                             unsigned short* __restrict__ APL) {
    int tid = threadIdx.x;
    int u = blockIdx.x * 4 + (tid >> 6);
    int rt = u / NVC, vc = u - rt * NVC;
    int rl = tid & 15, lh = (tid >> 4) & 3;
    int r = rt * 16 + rl;
    int v0 = (vc * 4 + lh) * 8;

    float f[24];
    if (r >= AR) {
#pragma unroll
        for (int i = 0; i < 24; i++) f[i] = 0.f;
    } else if (r == 218) {
#pragma unroll
        for (int i = 0; i < 24; i++) f[i] = (v0 + i / 3 < NV) ? 1.0f : 0.f;
    } else {
        const float* src = (r < NPOSE) ? (pd + (size_t)r * VSTR)
                         : (r < 217)   ? (sd + (size_t)(r - NPOSE) * VSTR)
                                       : vt;
        if (v0 + 8 <= NV) {
            const float2* p = (const float2*)(src + 3 * v0);
#pragma unroll
            for (int q = 0; q < 12; q++) {
                float2 t = p[q];
                f[2 * q] = t.x; f[2 * q + 1] = t.y;
            }
        } else {
#pragma unroll
            for (int i = 0; i < 24; i++)
                f[i] = (v0 + i / 3 < NV) ? src[3 * v0 + i] : 0.f;
        }
    }

    int lane = lh * 16 + rl;
#pragma unroll
    for (int a = 0; a < 3; a++) {
        union { unsigned short u16[8]; int4 v4; } H, L;
#pragma unroll
        for (int e = 0; e < 8; e++) bf_split(f[3 * e + a], H.u16[e], L.u16[e]);
        size_t off = (((size_t)(a * RTP + rt) * NVC + vc) * 64 + lane) * 8;
        *(int4*)&APH[off] = H.v4;
        *(int4*)&APL[off] = L.v4;
    }
}

// B packed BP[cf][vc][lane=lh*16+cl][e] = bf16(jr[v,k]*w[v,j]); coalesced writes.
__global__ __launch_bounds__(256) void k_cw2(const float* __restrict__ jr,
                                             const float* __restrict__ w,
                                             unsigned short* __restrict__ BPH,
                                             unsigned short* __restrict__ BPL) {
    int tid = threadIdx.x;
    int u = blockIdx.x * 4 + (tid >> 6);
    int cf = u / NVC, vc = u - cf * NVC;
    int cl = tid & 15, lh = (tid >> 4) & 3;
    int col = cf * 16 + cl;
    int v0 = (vc * 4 + lh) * 8;
    int k = col / NJ, j = col - k * NJ;
    bool okc = (col < NKJ);

    union { unsigned short u16[8]; int4 v4; } H, L;
#pragma unroll
    for (int e = 0; e < 8; e++) {
        int v = v0 + e;
        float val = (okc && v < NV) ? jr[v * NK + k] * w[v * NJ + j] : 0.f;
        bf_split(val, H.u16[e], L.u16[e]);
    }
    size_t off = (((size_t)cf * NVC + vc) * 64 + (lh * 16 + cl)) * 8;
    *(int4*)&BPH[off] = H.v4;
    *(int4*)&BPL[off] = L.v4;
}

// JS reduction (unchanged)
__global__ __launch_bounds__(256) void k_js2(const float* __restrict__ Jreg,
                                             const float* __restrict__ sd,
                                             const float* __restrict__ vt,
                                             float* __restrict__ JS) {
    int row = blockIdx.x % 11;
    int c   = blockIdx.x / 11;
    int tid = threadIdx.x;
    int lane = tid & 63;
    const float* src = (row < NBETA) ? (sd + (size_t)row * VSTR) : vt;

    float acc[72];
#pragma unroll
    for (int o = 0; o < 72; o++) acc[o] = 0.f;

    for (int iv = 0; iv < 4; ++iv) {
        int v = c * 1024 + iv * 256 + tid;
        float jrg[24];
        float s0 = 0.f, s1 = 0.f, s2 = 0.f;
        if (v < NV) {
#pragma unroll
            for (int q = 0; q < 6; q++) {
                float4 f = *(const float4*)&Jreg[v * NJ + q * 4];
                jrg[q * 4 + 0] = f.x; jrg[q * 4 + 1] = f.y;
                jrg[q * 4 + 2] = f.z; jrg[q * 4 + 3] = f.w;
            }
            s0 = src[3 * v]; s1 = src[3 * v + 1]; s2 = src[3 * v + 2];
        } else {
#pragma unroll
            for (int q = 0; q < 24; q++) jrg[q] = 0.f;
        }
#pragma unroll
        for (int j = 0; j < 24; j++) {
            acc[j * 3 + 0] += jrg[j] * s0;
            acc[j * 3 + 1] += jrg[j] * s1;
            acc[j * 3 + 2] += jrg[j] * s2;
        }
    }
#pragma unroll
    for (int o = 0; o < 72; o++) {
#pragma unroll
        for (int off = 1; off < 64; off <<= 1)
            acc[o] += __shfl_xor(acc[o], off);
    }
    if (lane == 0) {
#pragma unroll
        for (int o = 0; o < 72; o++) atomicAdd(&JS[row * 72 + o], acc[o]);
    }
}

// per-batch Rodrigues + chain (unchanged)
__global__ __launch_bounds__(64) void k_pose(const float* __restrict__ beta,
                                             const float* __restrict__ theta,
                                             const float* __restrict__ JS,
                                             float* __restrict__ coefT,
                                             float* __restrict__ Aw) {
    int n = blockIdx.x;
    int tid = threadIdx.x;
    __shared__ float Rs[24][9];
    __shared__ float Jl[24][3];
    __shared__ float G[24][12];

    if (tid < NJ) {
        int j = tid;
        float x = theta[n * 72 + j * 3 + 0];
        float y = theta[n * 72 + j * 3 + 1];
        float z = theta[n * 72 + j * 3 + 2];
        float ang = sqrtf(x * x + y * y + z * z + 1e-8f);
        float inv = 1.0f / ang;
        float rx = x * inv, ry = y * inv, rz = z * inv;
        float ct = cosf(ang), st = sinf(ang), oc = 1.0f - ct;
        float R[9];
        R[0] = ct + oc * rx * rx;  R[1] = -st * rz + oc * rx * ry; R[2] =  st * ry + oc * rx * rz;
        R[3] =  st * rz + oc * ry * rx; R[4] = ct + oc * ry * ry;  R[5] = -st * rx + oc * ry * rz;
        R[6] = -st * ry + oc * rz * rx; R[7] =  st * rx + oc * rz * ry; R[8] = ct + oc * rz * rz;
#pragma unroll
        for (int e = 0; e < 9; e++) Rs[j][e] = R[e];
        if (j >= 1) {
#pragma unroll
            for (int e = 0; e < 9; e++)
                coefT[(size_t)((j - 1) * 9 + e) * NB + n] =
                    R[e] - ((e == 0 || e == 4 || e == 8) ? 1.0f : 0.0f);
        }
    }
    if (tid < NBETA) coefT[(size_t)(NPOSE + tid) * NB + n] = beta[n * NBETA + tid];
    if (tid == 63)   coefT[(size_t)217 * NB + n] = 1.0f;
    __syncthreads();

    for (int idx = tid; idx < 72; idx += 64) {
        int j = idx / 3, a = idx - j * 3;
        float acc = JS[(NBETA * NJ + j) * 3 + a];
#pragma unroll
        for (int b = 0; b < NBETA; b++) acc += beta[n * NBETA + b] * JS[(b * NJ + j) * 3 + a];
        Jl[j][a] = acc;
    }
    __syncthreads();

    if (tid < 12) {
        int r = tid >> 2, cc = tid & 3;
        G[0][tid] = (cc < 3) ? Rs[0][r * 3 + cc] : Jl[0][r];
    }
    __syncthreads();

    const int PAR[24] = {0,0,0,0,1,2,3,4,5,6,7,8,9,9,9,12,13,14,16,17,18,19,20,21};
#pragma unroll
    for (int i = 1; i < NJ; i++) {
        int p = PAR[i];
        if (tid < 12) {
            int r = tid >> 2, cc = tid & 3;
            float g0 = G[p][r * 4 + 0], g1 = G[p][r * 4 + 1];
            float g2 = G[p][r * 4 + 2], g3 = G[p][r * 4 + 3];
            float val;
            if (cc < 3) {
                val = g0 * Rs[i][cc] + g1 * Rs[i][3 + cc] + g2 * Rs[i][6 + cc];
            } else {
                float t0 = Jl[i][0] - Jl[p][0];
                float t1 = Jl[i][1] - Jl[p][1];
                float t2 = Jl[i][2] - Jl[p][2];
                val = g0 * t0 + g1 * t1 + g2 * t2 + g3;
            }
            G[i][tid] = val;
        }
        __syncthreads();
    }

    for (int idx = tid; idx < 288; idx += 64) {
        int j = idx / 12, e = idx - j * 12;
        float val;
        if (e < 9) {
            int r = e / 3, cc = e - 3 * (e / 3);
            val = G[j][r * 4 + cc];
        } else {
            int r = e - 9;
            val = G[j][r * 4 + 3] -
                  (G[j][r * 4 + 0] * Jl[j][0] + G[j][r * 4 + 1] * Jl[j][1] +
                   G[j][r * 4 + 2] * Jl[j][2]);
        }
        Aw[(size_t)n * 288 + idx] = val;
    }
}

// MFMA GEMM, 128x64 tiles, KSPLIT=12 (576 blocks), ks-major XCD chunks.
// global_load_lds staging: 1 instr stages one 1KB fragment; double-buffered LDS;
// stage(t+1) issued BEFORE compute(t) so DMA flies under ds_read+MFMA (T3-minimal).
__global__ __launch_bounds__(256) void k_gemmP(const unsigned short* __restrict__ APH,
                                               const unsigned short* __restrict__ APL,
                                               const unsigned short* __restrict__ BPH,
                                               const unsigned short* __restrict__ BPL,
                                               float* __restrict__ OUTB) {
    int bid = blockIdx.x;
    int logical = (bid & 7) * 72 + (bid >> 3);    // 576 = 8 XCD chunks of 72
    int ks = logical / 48;                        // ks-major within chunk
    int rem = logical - ks * 48;
    int a  = rem >> 4;
    int mt = (rem >> 3) & 1;
    int nt = rem & 7;

    int tid = threadIdx.x;
    int lane = tid & 63, wv = tid >> 6;
    int wm = wv >> 1, wn = wv & 1;
    int lr = lane & 15, lc = lane >> 4;

    int aBase = a * RTP + mt * 8;   // 8 row-frags for this block
    int nBase = nt * 4;             // 4 col-frags

    __shared__ __align__(16) unsigned short stage[2][24 * 512];  // 2 x 24KB

    // stage one k-step (vc) into buffer b: 24 fragments, 6 per wave
#define STAGE(B, VC) do {                                                        \
    _Pragma("unroll")                                                            \
    for (int q = 0; q < 6; ++q) {                                                \
        int f = wv * 6 + q;                                                      \
        const unsigned short* g;                                                 \
        if (f < 16) {                                                            \
            int rt_l = f >> 1;                                                   \
            const unsigned short* pl = (f & 1) ? APL : APH;                      \
            g = pl + (((size_t)(aBase + rt_l) * NVC + (VC)) << 9) + lane * 8;    \
        } else {                                                                 \
            int cf_l = (f - 16) >> 1;                                            \
            const unsigned short* pl = (f & 1) ? BPL : BPH;                      \
            g = pl + (((size_t)(nBase + cf_l) * NVC + (VC)) << 9) + lane * 8;    \
        }                                                                        \
        __builtin_amdgcn_global_load_lds(                                        \
            (const __attribute__((address_space(1))) unsigned int*)g,            \
            (__attribute__((address_space(3))) unsigned int*)&stage[B][f * 512], \
            16, 0, 0);                                                           \
    }                                                                            \
} while (0)

    f32x4 acc[4][2] = {};
    int vc0 = ks * KSTEPS;

    STAGE(0, vc0);
    __syncthreads();

    int cur = 0;
    for (int t = 0; t < KSTEPS; ++t) {
        if (t + 1 < KSTEPS) STAGE(cur ^ 1, vc0 + t + 1);

        bf16x8 aH[4], aL[4], bH[2], bL[2];
#pragma unroll
        for (int mi = 0; mi < 4; mi++) {
            int rt_l = wm * 4 + mi;
            aH[mi] = *(const bf16x8*)&stage[cur][(2 * rt_l) * 512 + lane * 8];
            aL[mi] = *(const bf16x8*)&stage[cur][(2 * rt_l + 1) * 512 + lane * 8];
        }
#pragma unroll
        for (int ni = 0; ni < 2; ni++) {
            int cf_l = wn * 2 + ni;
            bH[ni] = *(const bf16x8*)&stage[cur][(16 + 2 * cf_l) * 512 + lane * 8];
            bL[ni] = *(const bf16x8*)&stage[cur][(16 + 2 * cf_l + 1) * 512 + lane * 8];
        }
#pragma unroll
        for (int mi = 0; mi < 4; mi++)
#pragma unroll
            for (int ni = 0; ni < 2; ni++) {
                acc[mi][ni] = __builtin_amdgcn_mfma_f32_16x16x32_bf16(aH[mi], bH[ni], acc[mi][ni], 0, 0, 0);
                acc[mi][ni] = __builtin_amdgcn_mfma_f32_16x16x32_bf16(aH[mi], bL[ni], acc[mi][ni], 0, 0, 0);
                acc[mi][ni] = __builtin_amdgcn_mfma_f32_16x16x32_bf16(aL[mi], bH[ni], acc[mi][ni], 0, 0, 0);
            }
        __syncthreads();   // drains DMA for t+1; protects buffer reuse
        cur ^= 1;
    }

#pragma unroll
    for (int mi = 0; mi < 4; mi++) {
        int r0 = mt * 128 + wm * 64 + mi * 16 + lc * 4;
        if (r0 >= AR) continue;
#pragma unroll
        for (int ni = 0; ni < 2; ni++) {
            int c = nt * 64 + wn * 32 + ni * 16 + lr;
            if (c >= NKJ) continue;
#pragma unroll
            for (int q = 0; q < 4; ++q) {
                int r = r0 + q;
                if (r < AR)
                    atomicAdd(&OUTB[(size_t)r * NCOL + a * NKJ + c], acc[mi][ni][q]);
            }
        }
    }
}

// M = coefT^T @ OUT, 32x64 tiles, LDS double-buffer (unchanged from r8)
__global__ __launch_bounds__(256) void k_gemmM(const float* __restrict__ coefT,
                                               const float* __restrict__ OUTB,
                                               float* __restrict__ M) {
    int bid = blockIdx.x;
    int mt = bid & 31, nt = bid >> 5;
    int mb = mt * 32, nb = nt * 64;
    __shared__ float Cs[2][32][32];
    __shared__ float Bs[2][32][64];
    int tid = threadIdx.x;
    int tm = tid & 15, tn = tid >> 4;

    float rc[4], rb[8];
#define LOADM(T) do {                                                    \
    int _kb = (T) * 32;                                                  \
    _Pragma("unroll") for (int p = 0; p < 4; p++) {                      \
        int idx = tid + p * 256;                                         \
        int kk = idx >> 5, nl = idx & 31;                                \
        int r = _kb + kk;                                                \
        rc[p] = (r < KR) ? coefT[(size_t)r * NB + mb + nl] : 0.f; }      \
    _Pragma("unroll") for (int p = 0; p < 8; p++) {                      \
        int idx = tid + p * 256;                                         \
        int kk = idx >> 6, m = idx & 63;                                 \
        int r = _kb + kk;                                                \
        int col = nb + m;                                                \
        rb[p] = (r < KR && col < NCOL) ? OUTB[(size_t)r * NCOL + col] : 0.f; } \
} while (0)

    LOADM(0);
    float acc[2][4] = {};
    int cur = 0;
    for (int t = 0; t < 7; ++t) {
#pragma unroll
        for (int p = 0; p < 4; p++) {
            int idx = tid + p * 256;
            Cs[cur][idx >> 5][idx & 31] = rc[p];
        }
#pragma unroll
        for (int p = 0; p < 8; p++) {
            int idx = tid + p * 256;
            Bs[cur][idx >> 6][idx & 63] = rb[p];
        }
        __syncthreads();
        if (t < 6) LOADM(t + 1);
#pragma unroll
        for (int kk = 0; kk < 32; kk++) {
            float2 cv = *(const float2*)&Cs[cur][kk][tm * 2];
            float4 bv = *(const float4*)&Bs[cur][kk][tn * 4];
            float cm[2] = {cv.x, cv.y};
            float bn[4] = {bv.x, bv.y, bv.z, bv.w};
#pragma unroll
            for (int i = 0; i < 2; i++)
#pragma unroll
                for (int j = 0; j < 4; j++) acc[i][j] += cm[i] * bn[j];
        }
        __syncthreads();
        cur ^= 1;
    }
#pragma unroll
    for (int i = 0; i < 2; i++) {
        int n = mb + tm * 2 + i;
#pragma unroll
        for (int j = 0; j < 4; j++) {
            int col = nb + tn * 4 + j;
            if (col < NCOL) M[(size_t)n * NCOL + col] = acc[i][j];
        }
    }
}

// joints: one thread per (n,k,a)
__global__ void k_joints(const float* __restrict__ M, const float* __restrict__ Aw,
                         const float* __restrict__ OUTB, float* __restrict__ out) {
    int idx = blockIdx.x * 256 + threadIdx.x;
    if (idx >= NB * NK * 3) return;
    int n = idx / (NK * 3);
    int rem = idx - n * (NK * 3);
    int k = rem / 3, a = rem - k * 3;
    const float* A = Aw + (size_t)n * 288;
    const float* Mn = M + (size_t)n * NCOL;
    float o = 0.f;
#pragma unroll
    for (int j = 0; j < NJ; j++) {
        int kj = k * NJ + j;
        const float* Aj = A + j * 12;
        o += Aj[a * 3 + 0] * Mn[kj]
           + Aj[a * 3 + 1] * Mn[NKJ + kj]
           + Aj[a * 3 + 2] * Mn[2 * NKJ + kj]
           + OUTB[(size_t)218 * NCOL + kj] * Aj[9 + a];
    }
    out[idx] = o;
}

extern "C" void kernel_launch(void* const* d_in, const int* in_sizes, int n_in,
                              void* d_out, int out_size, void* d_ws, size_t ws_size,
                              hipStream_t stream) {
    const float* beta  = (const float*)d_in[0];
    const float* theta = (const float*)d_in[1];
    const float* vt    = (const float*)d_in[2];
    const float* sd    = (const float*)d_in[3];
    const float* Jreg  = (const float*)d_in[4];
    const float* pd    = (const float*)d_in[5];
    const float* w     = (const float*)d_in[6];
    const float* jr    = (const float*)d_in[7];

    unsigned short* ush = (unsigned short*)d_ws;
    unsigned short* APH = ush;
    unsigned short* APL = APH + AP_PLANE;
    unsigned short* BPH = APL + AP_PLANE;
    unsigned short* BPL = BPH + BP_PLANE;
    float* fbase = (float*)(ush + USH_TOTAL);
    float* OUTB  = fbase;
    float* coefT = OUTB + SZ_OUT;
    float* Aw    = coefT + SZ_COEF;
    float* JS    = Aw + SZ_AW;
    float* M     = JS + SZ_JS;
    float* out   = (float*)d_out;

    hipMemsetAsync(OUTB, 0, (SZ_OUT + SZ_COEF + SZ_AW + SZ_JS) * sizeof(float), stream);
    k_at2<<<16 * NVC / 4, 256, 0, stream>>>(pd, sd, vt, APH, APL);
    k_cw2<<<CFP * NVC / 4, 256, 0, stream>>>(jr, w, BPH, BPL);
    k_js2<<<11 * 7, 256, 0, stream>>>(Jreg, sd, vt, JS);
    k_pose<<<NB, 64, 0, stream>>>(beta, theta, JS, coefT, Aw);
    k_gemmP<<<2 * 8 * 3 * KSPLIT, 256, 0, stream>>>(APH, APL, BPH, BPL, OUTB);
    k_gemmM<<<32 * 22, 256, 0, stream>>>(coefT, OUTB, M);
    k_joints<<<(NB * NK * 3 + 255) / 256, 256, 0, stream>>>(M, Aw, OUTB, out);
}

// Round 11
// 172.438 us; speedup vs baseline: 1.5521x; 1.0841x over previous
//
#include <hip/hip_runtime.h>

#define NB 1024
#define NV 6890
#define VP 6912
#define NJ 24
#define NBETA 10
#define NPOSE 207
#define NK 19
#define NKJ 456
#define NCOL 1368
#define KR 218
#define AR 219
#define VSTR 20670
#define RTP 16        // A row frags (256 rows padded)
#define NVC 216       // v chunks of 32
#define CFP 32        // B col frags (512 cols padded)
#define KSPLIT 12
#define KSTEPS 18     // NVC/KSPLIT
// gemmM2 fragment geometry
#define NF2 64        // n frags (1024/16)
#define KF2 7         // K frags (224/32)
#define CF2 88        // col frags (1408 padded)

typedef __attribute__((ext_vector_type(8))) short bf16x8;
typedef __attribute__((ext_vector_type(4))) float f32x4;

#define AP_PLANE ((size_t)3*RTP*NVC*64*8)   // 5,308,416 shorts
#define BP_PLANE ((size_t)CFP*NVC*64*8)     // 3,538,944 shorts
#define CP_PLANE ((size_t)NF2*KF2*64*8)     // 229,376 shorts
#define OP_PLANE ((size_t)CF2*KF2*64*8)     // 315,392 shorts
#define USH_TOTAL (2*AP_PLANE + 2*BP_PLANE + 2*CP_PLANE + 2*OP_PLANE)
#define SZ_OUT   ((size_t)AR*NCOL)
#define SZ_JS    (11ull*24*3)
#define SZ_COEF  ((size_t)KR*NB)
#define SZ_AW    ((size_t)NB*288)
#define SZ_M     ((size_t)NB*NCOL)

__device__ inline void bf_split(float x, unsigned short& h, unsigned short& l) {
    unsigned u = __float_as_uint(x);
    h = (unsigned short)(u >> 16);
    float hf = __uint_as_float((unsigned)h << 16);
    float lf = x - hf;
    l = (unsigned short)(__float_as_uint(lf) >> 16);
}

// ---- prep: at2 (blocks 0..863), cw2 (864..2591), js2 (2592..2668) ----
#define PREP_AT 864
#define PREP_CW 1728
#define PREP_JS 77

__global__ __launch_bounds__(256) void k_prep(const float* __restrict__ pd,
                                              const float* __restrict__ sd,
                                              const float* __restrict__ vt,
                                              const float* __restrict__ jr,
                                              const float* __restrict__ w,
                                              const float* __restrict__ Jreg,
                                              unsigned short* __restrict__ APH,
                                              unsigned short* __restrict__ APL,
                                              unsigned short* __restrict__ BPH,
                                              unsigned short* __restrict__ BPL,
                                              float* __restrict__ JS) {
    int bx = blockIdx.x;
    int tid = threadIdx.x;
    if (bx < PREP_AT) {
        // ---- A-plane pack ----
        int u = bx * 4 + (tid >> 6);
        int rt = u / NVC, vc = u - rt * NVC;
        int rl = tid & 15, lh = (tid >> 4) & 3;
        int r = rt * 16 + rl;
        int v0 = (vc * 4 + lh) * 8;
        float f[24];
        if (r >= AR) {
#pragma unroll
            for (int i = 0; i < 24; i++) f[i] = 0.f;
        } else if (r == 218) {
#pragma unroll
            for (int i = 0; i < 24; i++) f[i] = (v0 + i / 3 < NV) ? 1.0f : 0.f;
        } else {
            const float* src = (r < NPOSE) ? (pd + (size_t)r * VSTR)
                             : (r < 217)   ? (sd + (size_t)(r - NPOSE) * VSTR)
                                           : vt;
            if (v0 + 8 <= NV) {
                const float2* p = (const float2*)(src + 3 * v0);
#pragma unroll
                for (int q = 0; q < 12; q++) {
                    float2 t = p[q];
                    f[2 * q] = t.x; f[2 * q + 1] = t.y;
                }
            } else {
#pragma unroll
                for (int i = 0; i < 24; i++)
                    f[i] = (v0 + i / 3 < NV) ? src[3 * v0 + i] : 0.f;
            }
        }
        int lane = lh * 16 + rl;
#pragma unroll
        for (int a = 0; a < 3; a++) {
            union { unsigned short u16[8]; int4 v4; } H, L;
#pragma unroll
            for (int e = 0; e < 8; e++) bf_split(f[3 * e + a], H.u16[e], L.u16[e]);
            size_t off = (((size_t)(a * RTP + rt) * NVC + vc) * 64 + lane) * 8;
            *(int4*)&APH[off] = H.v4;
            *(int4*)&APL[off] = L.v4;
        }
    } else if (bx < PREP_AT + PREP_CW) {
        // ---- B-plane pack ----
        int u = (bx - PREP_AT) * 4 + (tid >> 6);
        int cf = u / NVC, vc = u - cf * NVC;
        int cl = tid & 15, lh = (tid >> 4) & 3;
        int col = cf * 16 + cl;
        int v0 = (vc * 4 + lh) * 8;
        int k = col / NJ, j = col - k * NJ;
        bool okc = (col < NKJ);
        union { unsigned short u16[8]; int4 v4; } H, L;
#pragma unroll
        for (int e = 0; e < 8; e++) {
            int v = v0 + e;
            float val = (okc && v < NV) ? jr[v * NK + k] * w[v * NJ + j] : 0.f;
            bf_split(val, H.u16[e], L.u16[e]);
        }
        size_t off = (((size_t)cf * NVC + vc) * 64 + (lh * 16 + cl)) * 8;
        *(int4*)&BPH[off] = H.v4;
        *(int4*)&BPL[off] = L.v4;
    } else {
        // ---- JS reduction ----
        int b2 = bx - PREP_AT - PREP_CW;
        int row = b2 % 11;
        int c   = b2 / 11;
        int lane = tid & 63;
        const float* src = (row < NBETA) ? (sd + (size_t)row * VSTR) : vt;
        float acc[72];
#pragma unroll
        for (int o = 0; o < 72; o++) acc[o] = 0.f;
        for (int iv = 0; iv < 4; ++iv) {
            int v = c * 1024 + iv * 256 + tid;
            float jrg[24];
            float s0 = 0.f, s1 = 0.f, s2 = 0.f;
            if (v < NV) {
#pragma unroll
                for (int q = 0; q < 6; q++) {
                    float4 f4 = *(const float4*)&Jreg[v * NJ + q * 4];
                    jrg[q * 4 + 0] = f4.x; jrg[q * 4 + 1] = f4.y;
                    jrg[q * 4 + 2] = f4.z; jrg[q * 4 + 3] = f4.w;
                }
                s0 = src[3 * v]; s1 = src[3 * v + 1]; s2 = src[3 * v + 2];
            } else {
#pragma unroll
                for (int q = 0; q < 24; q++) jrg[q] = 0.f;
            }
#pragma unroll
            for (int j = 0; j < 24; j++) {
                acc[j * 3 + 0] += jrg[j] * s0;
                acc[j * 3 + 1] += jrg[j] * s1;
                acc[j * 3 + 2] += jrg[j] * s2;
            }
        }
#pragma unroll
        for (int o = 0; o < 72; o++) {
#pragma unroll
            for (int off = 1; off < 64; off <<= 1)
                acc[o] += __shfl_xor(acc[o], off);
        }
        if (lane == 0) {
#pragma unroll
            for (int o = 0; o < 72; o++) atomicAdd(&JS[row * 72 + o], acc[o]);
        }
    }
}

// per-batch Rodrigues + chain (unchanged)
__global__ __launch_bounds__(64) void k_pose(const float* __restrict__ beta,
                                             const float* __restrict__ theta,
                                             const float* __restrict__ JS,
                                             float* __restrict__ coefT,
                                             float* __restrict__ Aw) {
    int n = blockIdx.x;
    int tid = threadIdx.x;
    __shared__ float Rs[24][9];
    __shared__ float Jl[24][3];
    __shared__ float G[24][12];

    if (tid < NJ) {
        int j = tid;
        float x = theta[n * 72 + j * 3 + 0];
        float y = theta[n * 72 + j * 3 + 1];
        float z = theta[n * 72 + j * 3 + 2];
        float ang = sqrtf(x * x + y * y + z * z + 1e-8f);
        float inv = 1.0f / ang;
        float rx = x * inv, ry = y * inv, rz = z * inv;
        float ct = cosf(ang), st = sinf(ang), oc = 1.0f - ct;
        float R[9];
        R[0] = ct + oc * rx * rx;  R[1] = -st * rz + oc * rx * ry; R[2] =  st * ry + oc * rx * rz;
        R[3] =  st * rz + oc * ry * rx; R[4] = ct + oc * ry * ry;  R[5] = -st * rx + oc * ry * rz;
        R[6] = -st * ry + oc * rz * rx; R[7] =  st * rx + oc * rz * ry; R[8] = ct + oc * rz * rz;
#pragma unroll
        for (int e = 0; e < 9; e++) Rs[j][e] = R[e];
        if (j >= 1) {
#pragma unroll
            for (int e = 0; e < 9; e++)
                coefT[(size_t)((j - 1) * 9 + e) * NB + n] =
                    R[e] - ((e == 0 || e == 4 || e == 8) ? 1.0f : 0.0f);
        }
    }
    if (tid < NBETA) coefT[(size_t)(NPOSE + tid) * NB + n] = beta[n * NBETA + tid];
    if (tid == 63)   coefT[(size_t)217 * NB + n] = 1.0f;
    __syncthreads();

    for (int idx = tid; idx < 72; idx += 64) {
        int j = idx / 3, a = idx - j * 3;
        float acc = JS[(NBETA * NJ + j) * 3 + a];
#pragma unroll
        for (int b = 0; b < NBETA; b++) acc += beta[n * NBETA + b] * JS[(b * NJ + j) * 3 + a];
        Jl[j][a] = acc;
    }
    __syncthreads();

    if (tid < 12) {
        int r = tid >> 2, cc = tid & 3;
        G[0][tid] = (cc < 3) ? Rs[0][r * 3 + cc] : Jl[0][r];
    }
    __syncthreads();

    const int PAR[24] = {0,0,0,0,1,2,3,4,5,6,7,8,9,9,9,12,13,14,16,17,18,19,20,21};
#pragma unroll
    for (int i = 1; i < NJ; i++) {
        int p = PAR[i];
        if (tid < 12) {
            int r = tid >> 2, cc = tid & 3;
            float g0 = G[p][r * 4 + 0], g1 = G[p][r * 4 + 1];
            float g2 = G[p][r * 4 + 2], g3 = G[p][r * 4 + 3];
            float val;
            if (cc < 3) {
                val = g0 * Rs[i][cc] + g1 * Rs[i][3 + cc] + g2 * Rs[i][6 + cc];
            } else {
                float t0 = Jl[i][0] - Jl[p][0];
                float t1 = Jl[i][1] - Jl[p][1];
                float t2 = Jl[i][2] - Jl[p][2];
                val = g0 * t0 + g1 * t1 + g2 * t2 + g3;
            }
            G[i][tid] = val;
        }
        __syncthreads();
    }

    for (int idx = tid; idx < 288; idx += 64) {
        int j = idx / 12, e = idx - j * 12;
        float val;
        if (e < 9) {
            int r = e / 3, cc = e - 3 * (e / 3);
            val = G[j][r * 4 + cc];
        } else {
            int r = e - 9;
            val = G[j][r * 4 + 3] -
                  (G[j][r * 4 + 0] * Jl[j][0] + G[j][r * 4 + 1] * Jl[j][1] +
                   G[j][r * 4 + 2] * Jl[j][2]);
        }
        Aw[(size_t)n * 288 + idx] = val;
    }
}

// gemmP: LDS-staged via global_load_lds, double-buffered (unchanged from r10 winner)
__global__ __launch_bounds__(256) void k_gemmP(const unsigned short* __restrict__ APH,
                                               const unsigned short* __restrict__ APL,
                                               const unsigned short* __restrict__ BPH,
                                               const unsigned short* __restrict__ BPL,
                                               float* __restrict__ OUTB) {
    int bid = blockIdx.x;
    int logical = (bid & 7) * 72 + (bid >> 3);
    int ks = logical / 48;
    int rem = logical - ks * 48;
    int a  = rem >> 4;
    int mt = (rem >> 3) & 1;
    int nt = rem & 7;

    int tid = threadIdx.x;
    int lane = tid & 63, wv = tid >> 6;
    int wm = wv >> 1, wn = wv & 1;
    int lr = lane & 15, lc = lane >> 4;

    int aBase = a * RTP + mt * 8;
    int nBase = nt * 4;

    __shared__ __align__(16) unsigned short stage[2][24 * 512];

#define STAGE(B, VC) do {                                                        \
    _Pragma("unroll")                                                            \
    for (int q = 0; q < 6; ++q) {                                                \
        int f = wv * 6 + q;                                                      \
        const unsigned short* g;                                                 \
        if (f < 16) {                                                            \
            int rt_l = f >> 1;                                                   \
            const unsigned short* pl = (f & 1) ? APL : APH;                      \
            g = pl + (((size_t)(aBase + rt_l) * NVC + (VC)) << 9) + lane * 8;    \
        } else {                                                                 \
            int cf_l = (f - 16) >> 1;                                            \
            const unsigned short* pl = (f & 1) ? BPL : BPH;                      \
            g = pl + (((size_t)(nBase + cf_l) * NVC + (VC)) << 9) + lane * 8;    \
        }                                                                        \
        __builtin_amdgcn_global_load_lds(                                        \
            (const __attribute__((address_space(1))) unsigned int*)g,            \
            (__attribute__((address_space(3))) unsigned int*)&stage[B][f * 512], \
            16, 0, 0);                                                           \
    }                                                                            \
} while (0)

    f32x4 acc[4][2] = {};
    int vc0 = ks * KSTEPS;

    STAGE(0, vc0);
    __syncthreads();

    int cur = 0;
    for (int t = 0; t < KSTEPS; ++t) {
        if (t + 1 < KSTEPS) STAGE(cur ^ 1, vc0 + t + 1);

        bf16x8 aH[4], aL[4], bH[2], bL[2];
#pragma unroll
        for (int mi = 0; mi < 4; mi++) {
            int rt_l = wm * 4 + mi;
            aH[mi] = *(const bf16x8*)&stage[cur][(2 * rt_l) * 512 + lane * 8];
            aL[mi] = *(const bf16x8*)&stage[cur][(2 * rt_l + 1) * 512 + lane * 8];
        }
#pragma unroll
        for (int ni = 0; ni < 2; ni++) {
            int cf_l = wn * 2 + ni;
            bH[ni] = *(const bf16x8*)&stage[cur][(16 + 2 * cf_l) * 512 + lane * 8];
            bL[ni] = *(const bf16x8*)&stage[cur][(16 + 2 * cf_l + 1) * 512 + lane * 8];
        }
#pragma unroll
        for (int mi = 0; mi < 4; mi++)
#pragma unroll
            for (int ni = 0; ni < 2; ni++) {
                acc[mi][ni] = __builtin_amdgcn_mfma_f32_16x16x32_bf16(aH[mi], bH[ni], acc[mi][ni], 0, 0, 0);
                acc[mi][ni] = __builtin_amdgcn_mfma_f32_16x16x32_bf16(aH[mi], bL[ni], acc[mi][ni], 0, 0, 0);
                acc[mi][ni] = __builtin_amdgcn_mfma_f32_16x16x32_bf16(aL[mi], bH[ni], acc[mi][ni], 0, 0, 0);
            }
        __syncthreads();
        cur ^= 1;
    }

#pragma unroll
    for (int mi = 0; mi < 4; mi++) {
        int r0 = mt * 128 + wm * 64 + mi * 16 + lc * 4;
        if (r0 >= AR) continue;
#pragma unroll
        for (int ni = 0; ni < 2; ni++) {
            int c = nt * 64 + wn * 32 + ni * 16 + lr;
            if (c >= NKJ) continue;
#pragma unroll
            for (int q = 0; q < 4; ++q) {
                int r = r0 + q;
                if (r < AR)
                    atomicAdd(&OUTB[(size_t)r * NCOL + a * NKJ + c], acc[mi][ni][q]);
            }
        }
    }
}

// pack coefT and OUT into MFMA fragment planes (hi/lo) for gemmM2.
// blocks [0,112): coef -> CP.  blocks [112,266): OUT -> OP.
__global__ __launch_bounds__(256) void k_pack(const float* __restrict__ coefT,
                                              const float* __restrict__ OUTB,
                                              unsigned short* __restrict__ CPH,
                                              unsigned short* __restrict__ CPL,
                                              unsigned short* __restrict__ OPH,
                                              unsigned short* __restrict__ OPL) {
    int gid = blockIdx.x * 256 + threadIdx.x;
    if (blockIdx.x < 112) {
        // idx = (nf*7 + kf)*64 + lane  over 64*7*64
        int idx = gid;
        int lane = idx & 63;
        int t = idx >> 6;
        int kf = t % KF2, nf = t / KF2;
        int n = nf * 16 + (lane & 15);
        int rbase = kf * 32 + (lane >> 4) * 8;
        union { unsigned short u16[8]; int4 v4; } H, L;
#pragma unroll
        for (int e = 0; e < 8; e++) {
            int r = rbase + e;
            float val = (r < KR) ? coefT[(size_t)r * NB + n] : 0.f;
            bf_split(val, H.u16[e], L.u16[e]);
        }
        *(int4*)&CPH[(size_t)idx * 8] = H.v4;
        *(int4*)&CPL[(size_t)idx * 8] = L.v4;
    } else {
        int idx = gid - 112 * 256;   // (cf*7 + kf)*64 + lane over 88*7*64
        int lane = idx & 63;
        int t = idx >> 6;
        int kf = t % KF2, cf = t / KF2;
        int col = cf * 16 + (lane & 15);
        int rbase = kf * 32 + (lane >> 4) * 8;
        union { unsigned short u16[8]; int4 v4; } H, L;
#pragma unroll
        for (int e = 0; e < 8; e++) {
            int r = rbase + e;
            float val = (r < KR && col < NCOL) ? OUTB[(size_t)r * NCOL + col] : 0.f;
            bf_split(val, H.u16[e], L.u16[e]);
        }
        *(int4*)&OPH[(size_t)idx * 8] = H.v4;
        *(int4*)&OPL[(size_t)idx * 8] = L.v4;
    }
}

// gemmM2: M[n][col] = sum_r coef[r][n]*OUT[r][col] via bf16 hi/lo MFMA.
// 64n x 64col blocks (16 x 22 grid), 4 waves 2x2, wave 32x32 = 2x2 frags, K=7 steps.
__global__ __launch_bounds__(256) void k_gemmM2(const unsigned short* __restrict__ CPH,
                                                const unsigned short* __restrict__ CPL,
                                                const unsigned short* __restrict__ OPH,
                                                const unsigned short* __restrict__ OPL,
                                                float* __restrict__ M) {
    int bid = blockIdx.x;
    int mtile = bid & 15, ctile = bid >> 4;   // 16 x 22
    int tid = threadIdx.x;
    int lane = tid & 63, wv = tid >> 6;
    int wm = wv >> 1, wn = wv & 1;
    int lr = lane & 15, lc = lane >> 4;

    f32x4 acc[2][2] = {};
#pragma unroll
    for (int kf = 0; kf < KF2; ++kf) {
        bf16x8 aH[2], aL[2], bH[2], bL[2];
#pragma unroll
        for (int mi = 0; mi < 2; mi++) {
            int nf = mtile * 4 + wm * 2 + mi;
            size_t off = ((size_t)(nf * KF2 + kf) * 64 + lane) * 8;
            aH[mi] = *(const bf16x8*)(CPH + off);
            aL[mi] = *(const bf16x8*)(CPL + off);
        }
#pragma unroll
        for (int ni = 0; ni < 2; ni++) {
            int cf = ctile * 4 + wn * 2 + ni;
            size_t off = ((size_t)(cf * KF2 + kf) * 64 + lane) * 8;
            bH[ni] = *(const bf16x8*)(OPH + off);
            bL[ni] = *(const bf16x8*)(OPL + off);
        }
#pragma unroll
        for (int mi = 0; mi < 2; mi++)
#pragma unroll
            for (int ni = 0; ni < 2; ni++) {
                acc[mi][ni] = __builtin_amdgcn_mfma_f32_16x16x32_bf16(aH[mi], bH[ni], acc[mi][ni], 0, 0, 0);
                acc[mi][ni] = __builtin_amdgcn_mfma_f32_16x16x32_bf16(aH[mi], bL[ni], acc[mi][ni], 0, 0, 0);
                acc[mi][ni] = __builtin_amdgcn_mfma_f32_16x16x32_bf16(aL[mi], bH[ni], acc[mi][ni], 0, 0, 0);
            }
    }

#pragma unroll
    for (int mi = 0; mi < 2; mi++) {
        int n0 = mtile * 64 + wm * 32 + mi * 16 + lc * 4;
#pragma unroll
        for (int ni = 0; ni < 2; ni++) {
            int col = ctile * 64 + wn * 32 + ni * 16 + lr;
            if (col >= NCOL) continue;
#pragma unroll
            for (int q = 0; q < 4; ++q)
                M[(size_t)(n0 + q) * NCOL + col] = acc[mi][ni][q];
        }
    }
}

// joints: one thread per (n,k,a)
__global__ void k_joints(const float* __restrict__ M, const float* __restrict__ Aw,
                         const float* __restrict__ OUTB, float* __restrict__ out) {
    int idx = blockIdx.x * 256 + threadIdx.x;
    if (idx >= NB * NK * 3) return;
    int n = idx / (NK * 3);
    int rem = idx - n * (NK * 3);
    int k = rem / 3, a = rem - k * 3;
    const float* A = Aw + (size_t)n * 288;
    const float* Mn = M + (size_t)n * NCOL;
    float o = 0.f;
#pragma unroll
    for (int j = 0; j < NJ; j++) {
        int kj = k * NJ + j;
        const float* Aj = A + j * 12;
        o += Aj[a * 3 + 0] * Mn[kj]
           + Aj[a * 3 + 1] * Mn[NKJ + kj]
           + Aj[a * 3 + 2] * Mn[2 * NKJ + kj]
           + OUTB[(size_t)218 * NCOL + kj] * Aj[9 + a];
    }
    out[idx] = o;
}

extern "C" void kernel_launch(void* const* d_in, const int* in_sizes, int n_in,
                              void* d_out, int out_size, void* d_ws, size_t ws_size,
                              hipStream_t stream) {
    const float* beta  = (const float*)d_in[0];
    const float* theta = (const float*)d_in[1];
    const float* vt    = (const float*)d_in[2];
    const float* sd    = (const float*)d_in[3];
    const float* Jreg  = (const float*)d_in[4];
    const float* pd    = (const float*)d_in[5];
    const float* w     = (const float*)d_in[6];
    const float* jr    = (const float*)d_in[7];

    unsigned short* ush = (unsigned short*)d_ws;
    unsigned short* APH = ush;
    unsigned short* APL = APH + AP_PLANE;
    unsigned short* BPH = APL + AP_PLANE;
    unsigned short* BPL = BPH + BP_PLANE;
    unsigned short* CPH = BPL + BP_PLANE;
    unsigned short* CPL = CPH + CP_PLANE;
    unsigned short* OPH = CPL + CP_PLANE;
    unsigned short* OPL = OPH + OP_PLANE;
    float* fbase = (float*)(ush + USH_TOTAL);
    float* OUTB  = fbase;                 // needs zero (atomics)
    float* JS    = OUTB + SZ_OUT;         // needs zero (atomics)
    float* coefT = JS + SZ_JS;
    float* Aw    = coefT + SZ_COEF;
    float* M     = Aw + SZ_AW;
    float* out   = (float*)d_out;

    hipMemsetAsync(OUTB, 0, (SZ_OUT + SZ_JS) * sizeof(float), stream);
    k_prep<<<PREP_AT + PREP_CW + PREP_JS, 256, 0, stream>>>(pd, sd, vt, jr, w, Jreg,
                                                            APH, APL, BPH, BPL, JS);
    k_pose<<<NB, 64, 0, stream>>>(beta, theta, JS, coefT, Aw);
    k_gemmP<<<2 * 8 * 3 * KSPLIT, 256, 0, stream>>>(APH, APL, BPH, BPL, OUTB);
    k_pack<<<266, 256, 0, stream>>>(coefT, OUTB, CPH, CPL, OPH, OPL);
    k_gemmM2<<<16 * 22, 256, 0, stream>>>(CPH, CPL, OPH, OPL, M);
    k_joints<<<(NB * NK * 3 + 255) / 256, 256, 0, stream>>>(M, Aw, OUTB, out);
}